// Round 11
// baseline (239.591 us; speedup 1.0000x reference)
//
#include <hip/hip_runtime.h>
#include <cstdint>
#include <cstddef>

typedef unsigned short u16;
typedef __attribute__((ext_vector_type(8))) __bf16 bf16x8;   // MFMA A/B operand
typedef __attribute__((ext_vector_type(4))) float floatx4;   // MFMA C/D operand

// dims
#define T_DIM   512
#define B_SZ    8
#define ROWS    4096      // T*B
#define OBS_D   256
#define D_IN    2048
#define NHEAD   16
#define NSTATE  64
#define PDIM    128
#define NUNITS  256
#define NACT    64
#define NSEG    4
#define SEGT    128       // T_DIM / NSEG
#define SLOT    (B_SZ * NHEAD * PDIM * NSTATE)   // 1048576 elems per seg-state slot
// BCm holds B(1024) | C(1024) | pad(128). GEMM computes N=2048 (16 tiles ->
// 512 blocks = exactly 2/CU) but WRITES with ldc=2176 (non-pow2 row stride;
// pow2 stride aliased L2 sets in seg_state/chunk_scan reads — r18 lesson).
#define BCSTR   2176      // row stride of BCm (u16 elems)
#define BCN     2048      // computed columns (B|C)

__host__ __device__ __forceinline__ float bf2f(u16 u) {
    union { uint32_t i; float f; } v; v.i = ((uint32_t)u) << 16; return v.f;
}
__host__ __device__ __forceinline__ u16 f2bf(float f) {
    union { float f; uint32_t i; } v; v.f = f;
    uint32_t r = v.i + 0x7FFFu + ((v.i >> 16) & 1u);
    return (u16)(r >> 16);
}

// async 16B/lane global->LDS (m97 pattern). lds ptr must be wave-uniform.
__device__ __forceinline__ void glds16(const u16* g, u16* l) {
    __builtin_amdgcn_global_load_lds(
        (__attribute__((address_space(1))) void*)g,
        (__attribute__((address_space(3))) void*)l, 16, 0, 0);
}

// ---------------- harness-required symbol (zero-work launch keeps it referenced) ----------------
__global__ __launch_bounds__(256) void ActorAgent_27625229647898_kernel(
        float* __restrict__ out, int n, float v) {
    for (int i = blockIdx.x * 256 + threadIdx.x; i < n; i += gridDim.x * 256)
        out[i] = v;
}

// ---------------- prep: all weight converts + transposes in ONE launch ----------------
__global__ __launch_bounds__(256) void prep(const float* __restrict__ obs,
                                            const float* __restrict__ W_dt,
                                            const float* __restrict__ W_in,
                                            const float* __restrict__ W_B,
                                            const float* __restrict__ W_C,
                                            const float* __restrict__ W_yo,
                                            const float* __restrict__ W_head,
                                            u16* __restrict__ obsb,
                                            u16* __restrict__ WinT, u16* __restrict__ WBCT,
                                            u16* __restrict__ WdtT,
                                            u16* __restrict__ WyoT, u16* __restrict__ WheadT) {
    int bid = blockIdx.x;
    if (bid < 160) {
        const int NOBS = ROWS * OBS_D;             // 1048576
        const int NDT  = D_IN * NHEAD;             // 32768
        for (int i = bid * 256 + threadIdx.x; i < NOBS + NDT; i += 160 * 256) {
            if (i < NOBS) obsb[i] = f2bf(obs[i]);
            else {
                int j = i - NOBS;                  // j = k*16 + n
                int k = j >> 4, n = j & 15;
                WdtT[n * D_IN + k] = f2bf(W_dt[j]);
            }
        }
        return;
    }
    bid -= 160;
    const float* src; u16* dst; int R, C, bx, by;
    if (bid < 512)       { src = W_in;   dst = WinT;   R = 256;  C = 2048; bx = bid & 63; by = bid >> 6; }
    else if (bid < 2560) { int i = bid - 512;  src = W_B;  dst = WBCT; R = 2048; C = 1024; bx = i & 31; by = i >> 5; }
    else if (bid < 4608) { int i = bid - 2560; src = W_C;  dst = WBCT + (size_t)1024 * 2048; R = 2048; C = 1024; bx = i & 31; by = i >> 5; }
    else if (bid < 5120) { int i = bid - 4608; src = W_yo; dst = WyoT; R = 2048; C = 256;  bx = i & 7;  by = i >> 3; }
    else                 { int i = bid - 5120; src = W_head; dst = WheadT; R = 256; C = 64; bx = i & 1; by = i >> 1; }
    __shared__ float t[32][33];
    int c0 = bx * 32, r0 = by * 32;
    int tx = threadIdx.x & 31, ty = threadIdx.x >> 5;
#pragma unroll
    for (int i = 0; i < 32; i += 8)
        t[ty + i][tx] = src[(size_t)(r0 + ty + i) * C + c0 + tx];
    __syncthreads();
#pragma unroll
    for (int i = 0; i < 32; i += 8)
        dst[(size_t)(c0 + ty + i) * R + r0 + tx] = f2bf(t[tx][ty + i]);
}

// ---------------- bt128: 128x128 bf16 MFMA GEMM, B^T (N,K), BK=32 glds staging ----------------
// r23: ONE barrier per K-iter, 4 LDS buffers, stage-after-compute, counted
// vmcnt(4). Proven (47.8 us, MfmaUtil 28%). r25: T2 swizzle reverted (4-way
// conflict hidden; swizzled source cost glds coalescing). r27: grid transpose
// reverted (FETCH 41->69.7 MB; original x=M-fastest gives each XCD 4 A-panels
// = 2 MB, L2-fits).
// r28: T5 setprio REMOVED here. Measured across 4 runs: no-setprio = 47.8/47.7
// (r23/r25), setprio = 50.0/52.3 (r26/r27). Mechanism (matches m190 GEMM
// negative): at 2 waves/SIMD the stage-after-compute schedule needs the
// CO-WAVE to issue its glds while this wave MFMAs; raising this wave's prio
// during the MFMA cluster delays that issue -> pipeline bubble. (bt64 keeps
// setprio: z-GEMM runs 1 wave/SIMD, nothing to arbitrate -> neutral.)
template <int ACT, int OUT_BF16, int HAS_BIAS>
__global__ __launch_bounds__(256) void gemm_bt128(const u16* __restrict__ A,
                                                  const u16* __restrict__ BT,
                                                  const float* __restrict__ bias,
                                                  void* __restrict__ Cout,
                                                  int M, int N, int K, int ldc) {
    __shared__ __align__(16) u16 sA[4][128 * 32];   // 4 x 8 KB
    __shared__ __align__(16) u16 sB[4][128 * 32];
    const int tid  = threadIdx.x;
    const int wave = tid >> 6, lane = tid & 63;
    const int quad = lane >> 4, lr = lane & 15;
    const int wm = wave & 1, wn = wave >> 1;
    const int m0 = blockIdx.x * 128, n0 = blockIdx.y * 128;
    const int r0 = wave * 32 + (lane >> 2);   // staged row per lane
    const int kel = (lane & 3) * 8;           // k offset (u16) per lane

    floatx4 acc[4][4];
#pragma unroll
    for (int i = 0; i < 4; i++)
#pragma unroll
        for (int j = 0; j < 4; j++)
#pragma unroll
            for (int r = 0; r < 4; r++) acc[i][j][r] = 0.f;

    const u16* apg = A + (size_t)(m0 + r0) * K + kel;
    const u16* bpg = BT + (size_t)(n0 + r0) * K + kel;
    const int lofs = (wave * 32) * 32;
    const int ntk = K >> 5;   // K tiles (8 or 64 for our shapes; always >= 2)

#define STAGE128(t, sb) do {                                        \
        int kk_ = (t) << 5;                                         \
        glds16(apg + kk_, &sA[sb][lofs]);                           \
        glds16(apg + (size_t)16 * K + kk_, &sA[sb][lofs + 16 * 32]);\
        glds16(bpg + kk_, &sB[sb][lofs]);                           \
        glds16(bpg + (size_t)16 * K + kk_, &sB[sb][lofs + 16 * 32]);\
    } while (0)

    STAGE128(0, 0);
    STAGE128(1, 1);
    for (int t = 0; t < ntk; ++t) {
        const int s = t & 3;
        if (t + 1 < ntk) {
            asm volatile("s_waitcnt vmcnt(4)" ::: "memory");   // tile t landed
        } else {
            asm volatile("s_waitcnt vmcnt(0)" ::: "memory");
        }
        __builtin_amdgcn_s_barrier();     // all waves' tile-t loads visible
        asm volatile("" ::: "memory");
        bf16x8 af[4], bfr[4];
#pragma unroll
        for (int i = 0; i < 4; i++)
            af[i] = *(const bf16x8*)&sA[s][(wm * 64 + i * 16 + lr) * 32 + quad * 8];
#pragma unroll
        for (int j = 0; j < 4; j++)
            bfr[j] = *(const bf16x8*)&sB[s][(wn * 64 + j * 16 + lr) * 32 + quad * 8];
#pragma unroll
        for (int i = 0; i < 4; i++)
#pragma unroll
            for (int j = 0; j < 4; j++)
                acc[i][j] = __builtin_amdgcn_mfma_f32_16x16x32_bf16(af[i], bfr[j], acc[i][j], 0, 0, 0);
        asm volatile("" ::: "memory");
        if (t + 2 < ntk) STAGE128(t + 2, (t + 2) & 3);
    }
#undef STAGE128
    // C/D layout: col = lane&15, row = quad*4 + reg
#pragma unroll
    for (int j = 0; j < 4; j++) {
        int col = n0 + wn * 64 + j * 16 + lr;
        float bvv = HAS_BIAS ? bias[col] : 0.f;
#pragma unroll
        for (int i = 0; i < 4; i++) {
#pragma unroll
            for (int r = 0; r < 4; r++) {
                int row = m0 + wm * 64 + i * 16 + quad * 4 + r;
                float v = acc[i][j][r] + bvv;
                if (ACT) v = fmaxf(v, 0.f);
                if (OUT_BF16) ((u16*)Cout)[(size_t)row * ldc + col] = f2bf(v);
                else          ((float*)Cout)[(size_t)row * ldc + col] = v;
            }
        }
    }
}

// ---------------- bt64: 64x64 bf16 MFMA GEMM, B^T layout, BK=64, 1-barrier 4-buf pipeline ----------------
// r24 swizzle KEPT: old read had row stride 128B -> 16-way conflict (5.7x,
// m136). Swizzle slot(3b) = (ks*4+quad)^(lr&7) + pre-swizzled global source
// (XOR involution, rule #21). setprio kept (1 wave/SIMD -> neutral-to-helpful;
// r27's non-BC portion was the best measured with it in).
template <int ACT, int OUT_BF16>
__global__ __launch_bounds__(256) void gemm_bt64(const u16* __restrict__ A,
                                                 const u16* __restrict__ BT,
                                                 const float* __restrict__ bias,
                                                 void* __restrict__ Cout,
                                                 int M, int N, int K) {
    __shared__ __align__(16) u16 sA[4][64 * 64];  // 4 x 8 KB
    __shared__ __align__(16) u16 sB[4][64 * 64];
    const int tid  = threadIdx.x;
    const int wave = tid >> 6, lane = tid & 63;
    const int quad = lane >> 4, lr = lane & 15;
    const int m0 = blockIdx.x * 64, n0 = blockIdx.y * 64;
    const int srl = lane >> 3;
    const int sc = (((lane & 7) ^ ((lane >> 3) & 7))) * 8;  // swizzled k-chunk (u16)
    const int rsw = lr & 7;                                 // read-side slot XOR

    floatx4 acc[4];
#pragma unroll
    for (int i = 0; i < 4; i++)
#pragma unroll
        for (int j = 0; j < 4; j++) acc[i][j] = 0.f;

    const u16* apg = A + (size_t)(m0 + wave * 16 + srl) * K + sc;
    const u16* bpg = BT + (size_t)(n0 + wave * 16 + srl) * K + sc;
    const int ntk = K >> 6;   // K tiles (32 or 4 for our shapes; always >= 2)

#define STAGE64(t, sb) do {                                            \
        int kk_ = (t) << 6;                                            \
        glds16(apg + kk_,                 &sA[sb][(wave * 16) * 64]);  \
        glds16(apg + (size_t)8 * K + kk_, &sA[sb][(wave * 16 + 8) * 64]);\
        glds16(bpg + kk_,                 &sB[sb][(wave * 16) * 64]);  \
        glds16(bpg + (size_t)8 * K + kk_, &sB[sb][(wave * 16 + 8) * 64]);\
    } while (0)

    STAGE64(0, 0);
    STAGE64(1, 1);
    for (int t = 0; t < ntk; ++t) {
        const int s = t & 3;
        if (t + 1 < ntk) {
            asm volatile("s_waitcnt vmcnt(4)" ::: "memory");
        } else {
            asm volatile("s_waitcnt vmcnt(0)" ::: "memory");
        }
        __builtin_amdgcn_s_barrier();
        asm volatile("" ::: "memory");
        __builtin_amdgcn_s_setprio(1);
#pragma unroll
        for (int ks = 0; ks < 2; ++ks) {
            bf16x8 af = *(const bf16x8*)&sA[s][(wave * 16 + lr) * 64 + ((ks * 4 + quad) ^ rsw) * 8];
#pragma unroll
            for (int nt = 0; nt < 4; nt++) {
                bf16x8 bf = *(const bf16x8*)&sB[s][(nt * 16 + lr) * 64 + ((ks * 4 + quad) ^ rsw) * 8];
                acc[nt] = __builtin_amdgcn_mfma_f32_16x16x32_bf16(af, bf, acc[nt], 0, 0, 0);
            }
        }
        __builtin_amdgcn_s_setprio(0);
        asm volatile("" ::: "memory");
        if (t + 2 < ntk) STAGE64(t + 2, (t + 2) & 3);
    }
#undef STAGE64
#pragma unroll
    for (int nt = 0; nt < 4; nt++) {
        int col = n0 + nt * 16 + lr;
        float bvv = bias ? bias[col] : 0.f;
#pragma unroll
        for (int r = 0; r < 4; r++) {
            int row = m0 + wave * 16 + quad * 4 + r;
            float v = acc[nt][r] + bvv;
            if (ACT) v = fmaxf(v, 0.f);
            if (OUT_BF16) ((u16*)Cout)[(size_t)row * N + col] = f2bf(v);
            else          ((float*)Cout)[(size_t)row * N + col] = v;
        }
    }
}

// ---------------- dtdecay: dtraw = x @ W_dt, fused softplus + decay ----------------
// r22: the wave's 2 rows are processed TOGETHER in one k-pass so the 32
// weight bf2f converts per k-step are shared. 256 blocks x 16 rows.
__global__ __launch_bounds__(512) void dtdecay(const u16* __restrict__ xb,
                                               const u16* __restrict__ WdtT,
                                               const float* __restrict__ dt_bias,
                                               const float* __restrict__ A_log,
                                               float* __restrict__ dtv,
                                               float* __restrict__ decayv) {
    __shared__ __align__(16) u16 sw[NHEAD * D_IN];   // 64 KB, [h][k]
    const int tid = threadIdx.x;
#pragma unroll
    for (int i = 0; i < 8; ++i) {
        int idx = (tid + i * 512) * 8;
        *(uint4*)&sw[idx] = *(const uint4*)(WdtT + idx);
    }
    __syncthreads();
    const int wave = tid >> 6, lane = tid & 63;
    const int q = lane >> 4, lr = lane & 15;
    const int row0 = blockIdx.x * 16 + wave * 2;
    const u16* xp0 = xb + (size_t)row0 * D_IN;
    const u16* xp1 = xb + (size_t)(row0 + 1) * D_IN;
    float acc0[4] = {0.f, 0.f, 0.f, 0.f};
    float acc1[4] = {0.f, 0.f, 0.f, 0.f};
#pragma unroll 4
    for (int k0 = 0; k0 < 16; ++k0) {
        const int kk = k0 * 128 + lr * 8;
        uint4 xv0 = *(const uint4*)(xp0 + kk);
        uint4 xv1 = *(const uint4*)(xp1 + kk);
        const u16* xu0 = (const u16*)&xv0;
        const u16* xu1 = (const u16*)&xv1;
        float xf0[8], xf1[8];
#pragma unroll
        for (int j = 0; j < 8; ++j) { xf0[j] = bf2f(xu0[j]); xf1[j] = bf2f(xu1[j]); }
#pragma unroll
        for (int j = 0; j < 4; ++j) {
            uint4 wv = *(const uint4*)&sw[(q * 4 + j) * D_IN + kk];
            const u16* wu = (const u16*)&wv;
#pragma unroll
            for (int jj = 0; jj < 8; ++jj) {
                float wf = bf2f(wu[jj]);
                acc0[j] = fmaf(xf0[jj], wf, acc0[j]);
                acc1[j] = fmaf(xf1[jj], wf, acc1[j]);
            }
        }
    }
    // reduce across the 16 lanes of each quad (masks 1,2,4,8 stay in-quad)
#pragma unroll
    for (int m = 1; m <= 8; m <<= 1)
#pragma unroll
        for (int j = 0; j < 4; ++j) {
            acc0[j] += __shfl_xor(acc0[j], m);
            acc1[j] += __shfl_xor(acc1[j], m);
        }
    if (lr == 0) {
#pragma unroll
        for (int j = 0; j < 4; ++j) {
            int h = q * 4 + j;
            float ae = expf(A_log[h]);
            float z0 = acc0[j] + dt_bias[h];
            float sp0 = (z0 > 20.f) ? z0 : log1pf(expf(z0));
            float z1 = acc1[j] + dt_bias[h];
            float sp1 = (z1 > 20.f) ? z1 : log1pf(expf(z1));
            dtv[row0 * NHEAD + h] = sp0;
            decayv[row0 * NHEAD + h] = expf(-ae * sp0);
            dtv[(row0 + 1) * NHEAD + h] = sp1;
            decayv[(row0 + 1) * NHEAD + h] = expf(-ae * sp1);
        }
    }
}

// ---------------- seg_state: segment-final states as weighted outer-product sum ----------------
__global__ __launch_bounds__(256) void seg_state(const u16* __restrict__ xw,
                                                 const u16* __restrict__ BCm,
                                                 const float* __restrict__ dtv,
                                                 const float* __restrict__ decayv,
                                                 float* __restrict__ Hbuf) {
    const int blk = blockIdx.x;
    const int seg = blk >> 7;
    const int b   = (blk >> 4) & 7;
    const int h   = blk & 15;
    const int tid = threadIdx.x;
    const int pgrp = tid >> 3;
    const int oct  = tid & 7;

    __shared__ __align__(16) u16 sx[SEGT][PDIM];
    __shared__ __align__(16) u16 sbm[SEGT][NSTATE];
    __shared__ float sw[SEGT];
    __shared__ float sdt[SEGT];
    __shared__ float sdec[SEGT];
    __shared__ float sP[32];

    const int t0 = seg * SEGT;

#pragma unroll
    for (int k = 0; k < 8; ++k) {
        int idx = tid + k * 256;
        int t = idx >> 4, c = (idx & 15) * 8;
        int r = (t0 + t) * B_SZ + b;
        *(uint4*)&sx[t][c] = *(const uint4*)(xw + (size_t)r * D_IN + h * PDIM + c);
    }
#pragma unroll
    for (int k = 0; k < 4; ++k) {
        int idx = tid + k * 256;
        int t = idx >> 3, c = (idx & 7) * 8;
        int r = (t0 + t) * B_SZ + b;
        *(uint4*)&sbm[t][c] = *(const uint4*)(BCm + (size_t)r * BCSTR + h * NSTATE + c);
    }
    if (tid < SEGT)            sdt[tid] = dtv[((t0 + tid) * B_SZ + b) * NHEAD + h];
    else if (tid < 2 * SEGT)   sdec[tid - SEGT] = decayv[((t0 + tid - SEGT) * B_SZ + b) * NHEAD + h];
    __syncthreads();

    if (tid < 32) {
        float p = 1.f;
        for (int i = 3; i >= 0; --i) {
            int t = tid * 4 + i;
            sw[t] = sdt[t] * p;
            p *= sdec[t];
        }
        sP[tid] = p;
    }
    __syncthreads();
    if (tid == 0) {
        float suf = 1.f;
        for (int q = 31; q >= 0; --q) { float tmp = sP[q]; sP[q] = suf; suf *= tmp; }
    }
    __syncthreads();
    if (tid < 32) {
        float m = sP[tid];
        for (int i = 0; i < 4; ++i) sw[tid * 4 + i] *= m;
    }
    __syncthreads();

    float acc[4][8];
#pragma unroll
    for (int i = 0; i < 4; i++)
#pragma unroll
        for (int j = 0; j < 8; j++) acc[i][j] = 0.f;

    for (int t = 0; t < SEGT; ++t) {
        float w = sw[t];
        const u16* xp = &sx[t][pgrp * 4];
        const u16* bp = &sbm[t][oct * 8];
        float xv[4], bv[8];
#pragma unroll
        for (int i = 0; i < 4; i++) xv[i] = w * bf2f(xp[i]);
#pragma unroll
        for (int j = 0; j < 8; j++) bv[j] = bf2f(bp[j]);
#pragma unroll
        for (int i = 0; i < 4; i++)
#pragma unroll
            for (int j = 0; j < 8; j++)
                acc[i][j] = fmaf(xv[i], bv[j], acc[i][j]);
    }

    float* base = Hbuf + (size_t)seg * SLOT +
                  (((size_t)b * NHEAD + h) * PDIM + pgrp * 4) * NSTATE + oct * 8;
#pragma unroll
    for (int i = 0; i < 4; i++) {
        *(float4*)(base + (size_t)i * NSTATE)     = make_float4(acc[i][0], acc[i][1], acc[i][2], acc[i][3]);
        *(float4*)(base + (size_t)i * NSTATE + 4) = make_float4(acc[i][4], acc[i][5], acc[i][6], acc[i][7]);
    }
}

// ---------------- prefix combine -> bf16 prefix states Hbf ----------------
__global__ __launch_bounds__(256) void seg_prefix(const float* __restrict__ Hbuf,
                                                  const float* __restrict__ decayv,
                                                  u16* __restrict__ Hbf) {
    const int blk = blockIdx.x;
    const int b  = blk >> 6;
    const int h  = (blk >> 2) & 15;
    const int ec = blk & 3;
    const int tid = threadIdx.x;

    __shared__ float sA[NSEG];

    if (tid < 64 * (NSEG - 2)) {
        int s = 1 + (tid >> 6);
        int i = tid & 63;
        int t = s * SEGT + i * 2;
        float p = decayv[(t * B_SZ + b) * NHEAD + h] *
                  decayv[((t + 1) * B_SZ + b) * NHEAD + h];
        p *= __shfl_xor(p, 1);
        p *= __shfl_xor(p, 2);
        p *= __shfl_xor(p, 4);
        p *= __shfl_xor(p, 8);
        p *= __shfl_xor(p, 16);
        p *= __shfl_xor(p, 32);
        if (i == 0) sA[s] = p;
    }
    __syncthreads();

    const size_t base = (((size_t)b * NHEAD + h) * PDIM * NSTATE) + (size_t)ec * 2048 + tid * 8;
    float4 P0 = *(const float4*)(Hbuf + base);
    float4 P1 = *(const float4*)(Hbuf + base + 4);
    u16 pk[8];
    pk[0] = f2bf(P0.x); pk[1] = f2bf(P0.y); pk[2] = f2bf(P0.z); pk[3] = f2bf(P0.w);
    pk[4] = f2bf(P1.x); pk[5] = f2bf(P1.y); pk[6] = f2bf(P1.z); pk[7] = f2bf(P1.w);
    *(uint4*)(Hbf + base) = *(const uint4*)pk;
#pragma unroll
    for (int s = 1; s <= NSEG - 2; ++s) {
        float a = sA[s];
        const float* slot = Hbuf + (size_t)s * SLOT + base;
        float4 h0 = *(const float4*)(slot);
        float4 h1 = *(const float4*)(slot + 4);
        P0.x = fmaf(a, P0.x, h0.x); P0.y = fmaf(a, P0.y, h0.y);
        P0.z = fmaf(a, P0.z, h0.z); P0.w = fmaf(a, P0.w, h0.w);
        P1.x = fmaf(a, P1.x, h1.x); P1.y = fmaf(a, P1.y, h1.y);
        P1.z = fmaf(a, P1.z, h1.z); P1.w = fmaf(a, P1.w, h1.w);
        pk[0] = f2bf(P0.x); pk[1] = f2bf(P0.y); pk[2] = f2bf(P0.z); pk[3] = f2bf(P0.w);
        pk[4] = f2bf(P1.x); pk[5] = f2bf(P1.y); pk[6] = f2bf(P1.z); pk[7] = f2bf(P1.w);
        *(uint4*)(Hbf + (size_t)s * SLOT + base) = *(const uint4*)pk;
    }
}

// ---------------- chunk_scan: fused S' build + Y = exp(L).C@Hp^T + S'@X^T ----------------
__global__ __launch_bounds__(256) void chunk_scan(const u16* __restrict__ BCm,
                                                  const float* __restrict__ dtv,
                                                  const float* __restrict__ decayv,
                                                  const u16* __restrict__ Hbf,
                                                  u16* __restrict__ xb) {
    __shared__ __align__(16) u16 sB_[128][68];   // B [t'][n]
    __shared__ __align__(16) u16 sC_[128][68];   // C [t][n]
    __shared__ __align__(16) u16 sS[128][132];   // S' [t][t']
    __shared__ __align__(16) u16 sXT[128][36];   // X^T [p][k-tile]
    __shared__ float sdt[SEGT], sL[SEGT], sEL[SEGT], stmp[32];

    const int blk = blockIdx.x;
    const int seg = blk >> 7, b = (blk >> 4) & 7, h = blk & 15;
    const int tid = threadIdx.x;
    const int wave = tid >> 6, lane = tid & 63;
    const int quad = lane >> 4, lr = lane & 15;
    const int wm = wave & 1, wn = wave >> 1;
    const int t0 = seg * SEGT;

#pragma unroll
    for (int it = 0; it < 4; ++it) {
        int idx = tid + it * 256;
        int t = idx >> 3, c = (idx & 7) * 8;
        int r = (t0 + t) * B_SZ + b;
        *(uint4*)&sB_[t][c] = *(const uint4*)(BCm + (size_t)r * BCSTR + h * NSTATE + c);
        *(uint4*)&sC_[t][c] = *(const uint4*)(BCm + (size_t)r * BCSTR + 1024 + h * NSTATE + c);
    }
    if (tid < SEGT) sdt[tid] = dtv[((t0 + tid) * B_SZ + b) * NHEAD + h];
    else if (tid < 2 * SEGT) {
        int t = tid - SEGT;
        sL[t] = __logf(fmaxf(decayv[((t0 + t) * B_SZ + b) * NHEAD + h], 1e-30f));
    }
    __syncthreads();
    if (tid < 32) {
        float s = 0.f, v[4];
#pragma unroll
        for (int i = 0; i < 4; ++i) { s += sL[tid * 4 + i]; v[i] = s; }
        stmp[tid] = s;
#pragma unroll
        for (int i = 0; i < 4; ++i) sL[tid * 4 + i] = v[i];
    }
    __syncthreads();
    if (tid == 0) {
        float run = 0.f;
        for (int q = 0; q < 32; ++q) { float c2 = stmp[q]; stmp[q] = run; run += c2; }
    }
    __syncthreads();
    if (tid < 32) {
        float off = stmp[tid];
#pragma unroll
        for (int i = 0; i < 4; ++i) sL[tid * 4 + i] += off;
    }
    __syncthreads();
    if (tid < SEGT) sEL[tid] = __expf(sL[tid]);

    floatx4 accS[4][4];
#pragma unroll
    for (int i = 0; i < 4; i++)
#pragma unroll
        for (int j = 0; j < 4; j++)
#pragma unroll
            for (int r = 0; r < 4; r++) accS[i][j][r] = 0.f;
#pragma unroll
    for (int k0 = 0; k0 < 64; k0 += 32) {
        bf16x8 af[4], bfr[4];
#pragma unroll
        for (int i = 0; i < 4; i++)
            af[i] = *(const bf16x8*)&sB_[wm * 64 + i * 16 + lr][k0 + quad * 8];
#pragma unroll
        for (int j = 0; j < 4; j++)
            bfr[j] = *(const bf16x8*)&sC_[wn * 64 + j * 16 + lr][k0 + quad * 8];
#pragma unroll
        for (int i = 0; i < 4; i++)
#pragma unroll
            for (int j = 0; j < 4; j++)
                accS[i][j] = __builtin_amdgcn_mfma_f32_16x16x32_bf16(af[i], bfr[j], accS[i][j], 0, 0, 0);
    }
#pragma unroll
    for (int j = 0; j < 4; j++) {
        int tt = wn * 64 + j * 16 + lr;
        float Lt = sL[tt];
#pragma unroll
        for (int i = 0; i < 4; i++) {
#pragma unroll
            for (int r = 0; r < 4; r++) {
                int tp = wm * 64 + i * 16 + quad * 4 + r;
                float v = 0.f;
                if (tp <= tt) v = accS[i][j][r] * sdt[tp] * __expf(Lt - sL[tp]);
                sS[tt][tp] = f2bf(v);
            }
        }
    }

    floatx4 acc[4][4];
#pragma unroll
    for (int i = 0; i < 4; i++)
#pragma unroll
        for (int j = 0; j < 4; j++)
#pragma unroll
            for (int r = 0; r < 4; r++) acc[i][j][r] = 0.f;
    __syncthreads();
    if (seg > 0) {
        const u16* hbase = Hbf + (size_t)(seg - 1) * SLOT + (((size_t)b * NHEAD + h) * PDIM) * NSTATE;
#pragma unroll
        for (int k0 = 0; k0 < 64; k0 += 32) {
            bf16x8 af[4], bfr[4];
#pragma unroll
            for (int i = 0; i < 4; i++)
                af[i] = *(const bf16x8*)&sC_[wm * 64 + i * 16 + lr][k0 + quad * 8];
#pragma unroll
            for (int j = 0; j < 4; j++)
                bfr[j] = *(const bf16x8*)(hbase + (size_t)(wn * 64 + j * 16 + lr) * NSTATE + k0 + quad * 8);
#pragma unroll
            for (int i = 0; i < 4; i++)
#pragma unroll
                for (int j = 0; j < 4; j++)
                    acc[i][j] = __builtin_amdgcn_mfma_f32_16x16x32_bf16(af[i], bfr[j], acc[i][j], 0, 0, 0);
        }
#pragma unroll
        for (int i = 0; i < 4; i++) {
#pragma unroll
            for (int r = 0; r < 4; r++) {
                float el = sEL[wm * 64 + i * 16 + quad * 4 + r];
#pragma unroll
                for (int j = 0; j < 4; j++) acc[i][j][r] *= el;
            }
        }
    }

    const int px = tid & 127, koh = (tid >> 7) * 16;
    for (int kc = 0; kc < 128; kc += 32) {
        u16 xv[16];
#pragma unroll
        for (int j2 = 0; j2 < 16; ++j2) {
            int tp = kc + koh + j2;
            xv[j2] = xb[(size_t)((t0 + tp) * B_SZ + b) * D_IN + h * PDIM + px];
        }
        __syncthreads();
        *(uint4*)&sXT[px][koh]     = *(const uint4*)&xv[0];
        *(uint4*)&sXT[px][koh + 8] = *(const uint4*)&xv[8];
        __syncthreads();
        bf16x8 af[4], bfr[4];
#pragma unroll
        for (int i = 0; i < 4; i++)
            af[i] = *(const bf16x8*)&sS[wm * 64 + i * 16 + lr][kc + quad * 8];
#pragma unroll
        for (int j = 0; j < 4; j++)
            bfr[j] = *(const bf16x8*)&sXT[wn * 64 + j * 16 + lr][quad * 8];
#pragma unroll
        for (int i = 0; i < 4; i++)
#pragma unroll
            for (int j = 0; j < 4; j++)
                acc[i][j] = __builtin_amdgcn_mfma_f32_16x16x32_bf16(af[i], bfr[j], acc[i][j], 0, 0, 0);
    }

#pragma unroll
    for (int j = 0; j < 4; j++) {
        int p = wn * 64 + j * 16 + lr;
#pragma unroll
        for (int i = 0; i < 4; i++) {
#pragma unroll
            for (int r = 0; r < 4; r++) {
                int t = wm * 64 + i * 16 + quad * 4 + r;
                xb[(size_t)((t0 + t) * B_SZ + b) * D_IN + h * PDIM + p] = f2bf(acc[i][j][r]);
            }
        }
    }
}

// ---------------- launch ----------------
extern "C" void kernel_launch(void* const* d_in, const int* in_sizes, int n_in,
                              void* d_out, int out_size, void* d_ws, size_t ws_size,
                              hipStream_t stream) {
    const float* obs     = (const float*)d_in[0];
    const float* W_in    = (const float*)d_in[1];
    const float* b_in    = (const float*)d_in[2];
    const float* A_log   = (const float*)d_in[3];
    const float* dt_bias = (const float*)d_in[4];
    const float* W_dt    = (const float*)d_in[5];
    const float* W_B     = (const float*)d_in[6];
    const float* W_C     = (const float*)d_in[7];
    const float* W_yo    = (const float*)d_in[8];
    const float* b_yo    = (const float*)d_in[9];
    const float* W_head  = (const float*)d_in[10];
    const float* b_head  = (const float*)d_in[11];

    char* ws = (char*)d_ws;
    size_t o = 0;
    u16*   xb     = (u16*)(ws + o);   o += (size_t)ROWS * D_IN * 2;            // 16 MB (x, then y in-place)
    u16*   BCm    = (u16*)(ws + o);   o += (size_t)ROWS * BCSTR * 2;           // 17.8 MB (B | C | pad)
    float* dtv    = (float*)(ws + o); o += (size_t)ROWS * NHEAD * 4;
    float* decayv = (float*)(ws + o); o += (size_t)ROWS * NHEAD * 4;
    u16*   zb     = (u16*)(ws + o);   o += (size_t)ROWS * NUNITS * 2;          // 2 MB
    float* Hseg   = (float*)(ws + o); o += (size_t)(NSEG - 1) * SLOT * 4;      // 12 MB
    u16*   Hbf    = (u16*)(ws + o);   o += (size_t)(NSEG - 1) * SLOT * 2;      // 6 MB
    u16*   obsb   = (u16*)(ws + o);   o += (size_t)ROWS * OBS_D * 2;           // 2 MB
    u16*   WinT   = (u16*)(ws + o);   o += (size_t)D_IN * OBS_D * 2;           // 1 MB
    u16*   WBCT   = (u16*)(ws + o);   o += (size_t)BCN * D_IN * 2;             // 8 MB
    u16*   WdtT   = (u16*)(ws + o);   o += (size_t)NHEAD * D_IN * 2;           // 64 KB
    u16*   WyoT   = (u16*)(ws + o);   o += (size_t)NUNITS * D_IN * 2;          // 1 MB
    u16*   WheadT = (u16*)(ws + o);   o += (size_t)NACT * NUNITS * 2;

    // zero-work launch of the harness-required symbol (kept referenced)
    ActorAgent_27625229647898_kernel<<<dim3(1), 256, 0, stream>>>((float*)d_out, 0, 0.f);

    // ---- all weight prep in one launch ----
    prep<<<dim3(160 + 5136), 256, 0, stream>>>(obs, W_dt, W_in, W_B, W_C, W_yo, W_head,
                                               obsb, WinT, WBCT, WdtT, WyoT, WheadT);

    // ---- x = relu(obs @ W_in + b_in) -> bf16 ----
    gemm_bt128<1, 1, 1><<<dim3(32, 16), 256, 0, stream>>>(obsb, WinT, b_in, xb, ROWS, D_IN, OBS_D, D_IN);
    // ---- dt = softplus(x @ W_dt + dt_bias); decay = exp(-exp(A_log)*dt) ----
    dtdecay<<<dim3(256), 512, 0, stream>>>(xb, WdtT, dt_bias, A_log, dtv, decayv);
    // ---- B|C projection: N=2048 (512 blocks = 2/CU), ldc=2176 (non-pow2 stride) ----
    gemm_bt128<0, 1, 0><<<dim3(32, 16), 256, 0, stream>>>(xb, WBCT, (const float*)nullptr, BCm, ROWS, BCN, D_IN, BCSTR);
    // ---- scan: A) segment-local final states ----
    seg_state<<<dim3((NSEG - 1) * 128), 256, 0, stream>>>(xb, BCm, dtv, decayv, Hseg);
    //          B) prefix combine -> bf16 ----
    seg_prefix<<<dim3(512), 256, 0, stream>>>(Hseg, decayv, Hbf);
    //          C) fused S' + Y, in-place over xb ----
    chunk_scan<<<dim3(NSEG * 128), 256, 0, stream>>>(BCm, dtv, decayv, Hbf, xb);
    // ---- z = relu(y @ W_yo + b_yo) -> bf16 ----
    gemm_bt64<1, 1><<<dim3(64, 4), 256, 0, stream>>>(xb, WyoT, b_yo, zb, ROWS, NUNITS, D_IN);
    // ---- logits = z @ W_head + b_head -> d_out (fp32) ----
    gemm_bt64<0, 0><<<dim3(64, 1), 256, 0, stream>>>(zb, WheadT, b_head, (float*)d_out, ROWS, NACT, NUNITS);
}

// Round 12
// 232.675 us; speedup vs baseline: 1.0297x; 1.0297x over previous
//
#include <hip/hip_runtime.h>
#include <cstdint>
#include <cstddef>

typedef unsigned short u16;
typedef __attribute__((ext_vector_type(8))) __bf16 bf16x8;   // MFMA A/B operand
typedef __attribute__((ext_vector_type(4))) float floatx4;   // MFMA C/D operand

// dims
#define T_DIM   512
#define B_SZ    8
#define ROWS    4096      // T*B
#define OBS_D   256
#define D_IN    2048
#define NHEAD   16
#define NSTATE  64
#define PDIM    128
#define NUNITS  256
#define NACT    64
#define NSEG    4
#define SEGT    128       // T_DIM / NSEG
#define SLOT    (B_SZ * NHEAD * PDIM * NSTATE)   // 1048576 elems per seg-state slot
// BCm holds B(1024) | C(1024) | pad(128). GEMM computes N=2048 (16 tiles ->
// 512 blocks = exactly 2/CU) but WRITES with ldc=2176 (non-pow2 row stride;
// pow2 stride aliased L2 sets in seg_state/chunk_scan reads — r18 lesson).
#define BCSTR   2176      // row stride of BCm (u16 elems)
#define BCN     2048      // computed columns (B|C)

__host__ __device__ __forceinline__ float bf2f(u16 u) {
    union { uint32_t i; float f; } v; v.i = ((uint32_t)u) << 16; return v.f;
}
__host__ __device__ __forceinline__ u16 f2bf(float f) {
    union { float f; uint32_t i; } v; v.f = f;
    uint32_t r = v.i + 0x7FFFu + ((v.i >> 16) & 1u);
    return (u16)(r >> 16);
}

// async 16B/lane global->LDS (m97 pattern). lds ptr must be wave-uniform.
__device__ __forceinline__ void glds16(const u16* g, u16* l) {
    __builtin_amdgcn_global_load_lds(
        (__attribute__((address_space(1))) void*)g,
        (__attribute__((address_space(3))) void*)l, 16, 0, 0);
}

// ---------------- harness-required symbol (zero-work launch keeps it referenced) ----------------
__global__ __launch_bounds__(256) void ActorAgent_27625229647898_kernel(
        float* __restrict__ out, int n, float v) {
    for (int i = blockIdx.x * 256 + threadIdx.x; i < n; i += gridDim.x * 256)
        out[i] = v;
}

// ---------------- prep: all weight converts + transposes in ONE launch ----------------
__global__ __launch_bounds__(256) void prep(const float* __restrict__ obs,
                                            const float* __restrict__ W_dt,
                                            const float* __restrict__ W_in,
                                            const float* __restrict__ W_B,
                                            const float* __restrict__ W_C,
                                            const float* __restrict__ W_yo,
                                            const float* __restrict__ W_head,
                                            u16* __restrict__ obsb,
                                            u16* __restrict__ WinT, u16* __restrict__ WBCT,
                                            u16* __restrict__ WdtT,
                                            u16* __restrict__ WyoT, u16* __restrict__ WheadT) {
    int bid = blockIdx.x;
    if (bid < 160) {
        const int NOBS = ROWS * OBS_D;             // 1048576
        const int NDT  = D_IN * NHEAD;             // 32768
        for (int i = bid * 256 + threadIdx.x; i < NOBS + NDT; i += 160 * 256) {
            if (i < NOBS) obsb[i] = f2bf(obs[i]);
            else {
                int j = i - NOBS;                  // j = k*16 + n
                int k = j >> 4, n = j & 15;
                WdtT[n * D_IN + k] = f2bf(W_dt[j]);
            }
        }
        return;
    }
    bid -= 160;
    const float* src; u16* dst; int R, C, bx, by;
    if (bid < 512)       { src = W_in;   dst = WinT;   R = 256;  C = 2048; bx = bid & 63; by = bid >> 6; }
    else if (bid < 2560) { int i = bid - 512;  src = W_B;  dst = WBCT; R = 2048; C = 1024; bx = i & 31; by = i >> 5; }
    else if (bid < 4608) { int i = bid - 2560; src = W_C;  dst = WBCT + (size_t)1024 * 2048; R = 2048; C = 1024; bx = i & 31; by = i >> 5; }
    else if (bid < 5120) { int i = bid - 4608; src = W_yo; dst = WyoT; R = 2048; C = 256;  bx = i & 7;  by = i >> 3; }
    else                 { int i = bid - 5120; src = W_head; dst = WheadT; R = 256; C = 64; bx = i & 1; by = i >> 1; }
    __shared__ float t[32][33];
    int c0 = bx * 32, r0 = by * 32;
    int tx = threadIdx.x & 31, ty = threadIdx.x >> 5;
#pragma unroll
    for (int i = 0; i < 32; i += 8)
        t[ty + i][tx] = src[(size_t)(r0 + ty + i) * C + c0 + tx];
    __syncthreads();
#pragma unroll
    for (int i = 0; i < 32; i += 8)
        dst[(size_t)(c0 + ty + i) * R + r0 + tx] = f2bf(t[tx][ty + i]);
}

// ---------------- bt128: 128x128 bf16 MFMA GEMM, B^T (N,K), BK=64 swizzled staging ----------------
// r29: BK 32 -> 64. BC-GEMM was sync-bound: 1789 cyc/iter vs ~400 compute at
// 2 waves/SIMD; halving iters (64->32) halves barriers+waits and doubles
// MFMA-per-barrier to 32. r14's BK=64 failure was the unswizzled [row][128B]
// layout (bank = f(slot) only -> 16-way conflict); with the bt64-proven XOR
// (slot = chunk ^ (row&7), pre-swizzled global source per rule #21) the
// fragment read is 4-way — the level the BK=32 kernel already hides. Permute
// stays within each row's 128B (bt64 pattern; r24's bad case was within-64B).
// Schedule (2 buffers, 64 KB LDS, 2 blocks/CU): vmcnt(0) -> barrier ->
// STAGE(t+1 -> s^1) -> 32 MFMA(s). The wait covers loads issued a full
// compute phase ago; the barrier proves both tile-t visibility and buf-reuse
// safety. One barrier + one wait per 64-K (4x less sync than r22's schedule).
// History: r25 reverted in-kernel T2 (hidden 4-way + source-coalescing cost);
// r27 reverted grid transpose (FETCH 41->70 MB); r28 removed setprio
// (47.8/47.7 without vs 50.0/52.3 with, across 4 runs).
template <int ACT, int OUT_BF16, int HAS_BIAS>
__global__ __launch_bounds__(256) void gemm_bt128(const u16* __restrict__ A,
                                                  const u16* __restrict__ BT,
                                                  const float* __restrict__ bias,
                                                  void* __restrict__ Cout,
                                                  int M, int N, int K, int ldc) {
    __shared__ __align__(16) u16 sA[2][128 * 64];   // 2 x 16 KB
    __shared__ __align__(16) u16 sB[2][128 * 64];
    const int tid  = threadIdx.x;
    const int wave = tid >> 6, lane = tid & 63;
    const int quad = lane >> 4, lr = lane & 15;
    const int wm = wave & 1, wn = wave >> 1;
    const int m0 = blockIdx.x * 128, n0 = blockIdx.y * 128;
    const int r0 = wave * 32 + (lane >> 3);                   // staged row per lane
    const int kel = (((lane & 7) ^ ((lane >> 3) & 7))) * 8;   // swizzled k-chunk (u16)
    const int rsw = lr & 7;                                   // read-side slot XOR

    floatx4 acc[4][4];
#pragma unroll
    for (int i = 0; i < 4; i++)
#pragma unroll
        for (int j = 0; j < 4; j++)
#pragma unroll
            for (int r = 0; r < 4; r++) acc[i][j][r] = 0.f;

    const u16* apg = A + (size_t)(m0 + r0) * K + kel;
    const u16* bpg = BT + (size_t)(n0 + r0) * K + kel;
    const int ntk = K >> 6;   // K tiles (4 or 32 for our shapes; always >= 2)

#define STAGE128(t, sb) do {                                                   \
        int kk_ = (t) << 6;                                                    \
        _Pragma("unroll")                                                      \
        for (int g = 0; g < 4; ++g) {                                          \
            glds16(apg + (size_t)(g * 8) * K + kk_,                            \
                   &sA[sb][(wave * 32 + g * 8) * 64]);                         \
            glds16(bpg + (size_t)(g * 8) * K + kk_,                            \
                   &sB[sb][(wave * 32 + g * 8) * 64]);                         \
        }                                                                      \
    } while (0)

    STAGE128(0, 0);
    for (int t = 0; t < ntk; ++t) {
        const int s = t & 1;
        asm volatile("s_waitcnt vmcnt(0)" ::: "memory");   // tile t landed
        __builtin_amdgcn_s_barrier();   // all waves' tile-t loads visible;
                                        // all waves done reading tile t-1
        asm volatile("" ::: "memory");
        if (t + 1 < ntk) STAGE128(t + 1, s ^ 1);
#pragma unroll
        for (int ks = 0; ks < 2; ++ks) {
            bf16x8 af[4], bfr[4];
#pragma unroll
            for (int i = 0; i < 4; i++)
                af[i] = *(const bf16x8*)&sA[s][(wm * 64 + i * 16 + lr) * 64 + ((ks * 4 + quad) ^ rsw) * 8];
#pragma unroll
            for (int j = 0; j < 4; j++)
                bfr[j] = *(const bf16x8*)&sB[s][(wn * 64 + j * 16 + lr) * 64 + ((ks * 4 + quad) ^ rsw) * 8];
#pragma unroll
            for (int i = 0; i < 4; i++)
#pragma unroll
                for (int j = 0; j < 4; j++)
                    acc[i][j] = __builtin_amdgcn_mfma_f32_16x16x32_bf16(af[i], bfr[j], acc[i][j], 0, 0, 0);
        }
        asm volatile("" ::: "memory");
    }
#undef STAGE128
    // C/D layout: col = lane&15, row = quad*4 + reg
#pragma unroll
    for (int j = 0; j < 4; j++) {
        int col = n0 + wn * 64 + j * 16 + lr;
        float bvv = HAS_BIAS ? bias[col] : 0.f;
#pragma unroll
        for (int i = 0; i < 4; i++) {
#pragma unroll
            for (int r = 0; r < 4; r++) {
                int row = m0 + wm * 64 + i * 16 + quad * 4 + r;
                float v = acc[i][j][r] + bvv;
                if (ACT) v = fmaxf(v, 0.f);
                if (OUT_BF16) ((u16*)Cout)[(size_t)row * ldc + col] = f2bf(v);
                else          ((float*)Cout)[(size_t)row * ldc + col] = v;
            }
        }
    }
}

// ---------------- bt64: 64x64 bf16 MFMA GEMM, B^T layout, BK=64, 1-barrier 4-buf pipeline ----------------
// r24 swizzle KEPT: old read had row stride 128B -> 16-way conflict (5.7x,
// m136). Swizzle slot(3b) = (ks*4+quad)^(lr&7) + pre-swizzled global source
// (XOR involution, rule #21). setprio kept (1 wave/SIMD -> neutral-to-helpful).
template <int ACT, int OUT_BF16>
__global__ __launch_bounds__(256) void gemm_bt64(const u16* __restrict__ A,
                                                 const u16* __restrict__ BT,
                                                 const float* __restrict__ bias,
                                                 void* __restrict__ Cout,
                                                 int M, int N, int K) {
    __shared__ __align__(16) u16 sA[4][64 * 64];  // 4 x 8 KB
    __shared__ __align__(16) u16 sB[4][64 * 64];
    const int tid  = threadIdx.x;
    const int wave = tid >> 6, lane = tid & 63;
    const int quad = lane >> 4, lr = lane & 15;
    const int m0 = blockIdx.x * 64, n0 = blockIdx.y * 64;
    const int srl = lane >> 3;
    const int sc = (((lane & 7) ^ ((lane >> 3) & 7))) * 8;  // swizzled k-chunk (u16)
    const int rsw = lr & 7;                                 // read-side slot XOR

    floatx4 acc[4];
#pragma unroll
    for (int i = 0; i < 4; i++)
#pragma unroll
        for (int j = 0; j < 4; j++) acc[i][j] = 0.f;

    const u16* apg = A + (size_t)(m0 + wave * 16 + srl) * K + sc;
    const u16* bpg = BT + (size_t)(n0 + wave * 16 + srl) * K + sc;
    const int ntk = K >> 6;   // K tiles (32 or 4 for our shapes; always >= 2)

#define STAGE64(t, sb) do {                                            \
        int kk_ = (t) << 6;                                            \
        glds16(apg + kk_,                 &sA[sb][(wave * 16) * 64]);  \
        glds16(apg + (size_t)8 * K + kk_, &sA[sb][(wave * 16 + 8) * 64]);\
        glds16(bpg + kk_,                 &sB[sb][(wave * 16) * 64]);  \
        glds16(bpg + (size_t)8 * K + kk_, &sB[sb][(wave * 16 + 8) * 64]);\
    } while (0)

    STAGE64(0, 0);
    STAGE64(1, 1);
    for (int t = 0; t < ntk; ++t) {
        const int s = t & 3;
        if (t + 1 < ntk) {
            asm volatile("s_waitcnt vmcnt(4)" ::: "memory");
        } else {
            asm volatile("s_waitcnt vmcnt(0)" ::: "memory");
        }
        __builtin_amdgcn_s_barrier();
        asm volatile("" ::: "memory");
        __builtin_amdgcn_s_setprio(1);
#pragma unroll
        for (int ks = 0; ks < 2; ++ks) {
            bf16x8 af = *(const bf16x8*)&sA[s][(wave * 16 + lr) * 64 + ((ks * 4 + quad) ^ rsw) * 8];
#pragma unroll
            for (int nt = 0; nt < 4; nt++) {
                bf16x8 bf = *(const bf16x8*)&sB[s][(nt * 16 + lr) * 64 + ((ks * 4 + quad) ^ rsw) * 8];
                acc[nt] = __builtin_amdgcn_mfma_f32_16x16x32_bf16(af, bf, acc[nt], 0, 0, 0);
            }
        }
        __builtin_amdgcn_s_setprio(0);
        asm volatile("" ::: "memory");
        if (t + 2 < ntk) STAGE64(t + 2, (t + 2) & 3);
    }
#undef STAGE64
#pragma unroll
    for (int nt = 0; nt < 4; nt++) {
        int col = n0 + nt * 16 + lr;
        float bvv = bias ? bias[col] : 0.f;
#pragma unroll
        for (int r = 0; r < 4; r++) {
            int row = m0 + wave * 16 + quad * 4 + r;
            float v = acc[nt][r] + bvv;
            if (ACT) v = fmaxf(v, 0.f);
            if (OUT_BF16) ((u16*)Cout)[(size_t)row * N + col] = f2bf(v);
            else          ((float*)Cout)[(size_t)row * N + col] = v;
        }
    }
}

// ---------------- dtdecay: dtraw = x @ W_dt, fused softplus + decay ----------------
// r22: the wave's 2 rows are processed TOGETHER in one k-pass so the 32
// weight bf2f converts per k-step are shared. 256 blocks x 16 rows.
__global__ __launch_bounds__(512) void dtdecay(const u16* __restrict__ xb,
                                               const u16* __restrict__ WdtT,
                                               const float* __restrict__ dt_bias,
                                               const float* __restrict__ A_log,
                                               float* __restrict__ dtv,
                                               float* __restrict__ decayv) {
    __shared__ __align__(16) u16 sw[NHEAD * D_IN];   // 64 KB, [h][k]
    const int tid = threadIdx.x;
#pragma unroll
    for (int i = 0; i < 8; ++i) {
        int idx = (tid + i * 512) * 8;
        *(uint4*)&sw[idx] = *(const uint4*)(WdtT + idx);
    }
    __syncthreads();
    const int wave = tid >> 6, lane = tid & 63;
    const int q = lane >> 4, lr = lane & 15;
    const int row0 = blockIdx.x * 16 + wave * 2;
    const u16* xp0 = xb + (size_t)row0 * D_IN;
    const u16* xp1 = xb + (size_t)(row0 + 1) * D_IN;
    float acc0[4] = {0.f, 0.f, 0.f, 0.f};
    float acc1[4] = {0.f, 0.f, 0.f, 0.f};
#pragma unroll 4
    for (int k0 = 0; k0 < 16; ++k0) {
        const int kk = k0 * 128 + lr * 8;
        uint4 xv0 = *(const uint4*)(xp0 + kk);
        uint4 xv1 = *(const uint4*)(xp1 + kk);
        const u16* xu0 = (const u16*)&xv0;
        const u16* xu1 = (const u16*)&xv1;
        float xf0[8], xf1[8];
#pragma unroll
        for (int j = 0; j < 8; ++j) { xf0[j] = bf2f(xu0[j]); xf1[j] = bf2f(xu1[j]); }
#pragma unroll
        for (int j = 0; j < 4; ++j) {
            uint4 wv = *(const uint4*)&sw[(q * 4 + j) * D_IN + kk];
            const u16* wu = (const u16*)&wv;
#pragma unroll
            for (int jj = 0; jj < 8; ++jj) {
                float wf = bf2f(wu[jj]);
                acc0[j] = fmaf(xf0[jj], wf, acc0[j]);
                acc1[j] = fmaf(xf1[jj], wf, acc1[j]);
            }
        }
    }
    // reduce across the 16 lanes of each quad (masks 1,2,4,8 stay in-quad)
#pragma unroll
    for (int m = 1; m <= 8; m <<= 1)
#pragma unroll
        for (int j = 0; j < 4; ++j) {
            acc0[j] += __shfl_xor(acc0[j], m);
            acc1[j] += __shfl_xor(acc1[j], m);
        }
    if (lr == 0) {
#pragma unroll
        for (int j = 0; j < 4; ++j) {
            int h = q * 4 + j;
            float ae = expf(A_log[h]);
            float z0 = acc0[j] + dt_bias[h];
            float sp0 = (z0 > 20.f) ? z0 : log1pf(expf(z0));
            float z1 = acc1[j] + dt_bias[h];
            float sp1 = (z1 > 20.f) ? z1 : log1pf(expf(z1));
            dtv[row0 * NHEAD + h] = sp0;
            decayv[row0 * NHEAD + h] = expf(-ae * sp0);
            dtv[(row0 + 1) * NHEAD + h] = sp1;
            decayv[(row0 + 1) * NHEAD + h] = expf(-ae * sp1);
        }
    }
}

// ---------------- seg_state: segment-final states as weighted outer-product sum ----------------
__global__ __launch_bounds__(256) void seg_state(const u16* __restrict__ xw,
                                                 const u16* __restrict__ BCm,
                                                 const float* __restrict__ dtv,
                                                 const float* __restrict__ decayv,
                                                 float* __restrict__ Hbuf) {
    const int blk = blockIdx.x;
    const int seg = blk >> 7;
    const int b   = (blk >> 4) & 7;
    const int h   = blk & 15;
    const int tid = threadIdx.x;
    const int pgrp = tid >> 3;
    const int oct  = tid & 7;

    __shared__ __align__(16) u16 sx[SEGT][PDIM];
    __shared__ __align__(16) u16 sbm[SEGT][NSTATE];
    __shared__ float sw[SEGT];
    __shared__ float sdt[SEGT];
    __shared__ float sdec[SEGT];
    __shared__ float sP[32];

    const int t0 = seg * SEGT;

#pragma unroll
    for (int k = 0; k < 8; ++k) {
        int idx = tid + k * 256;
        int t = idx >> 4, c = (idx & 15) * 8;
        int r = (t0 + t) * B_SZ + b;
        *(uint4*)&sx[t][c] = *(const uint4*)(xw + (size_t)r * D_IN + h * PDIM + c);
    }
#pragma unroll
    for (int k = 0; k < 4; ++k) {
        int idx = tid + k * 256;
        int t = idx >> 3, c = (idx & 7) * 8;
        int r = (t0 + t) * B_SZ + b;
        *(uint4*)&sbm[t][c] = *(const uint4*)(BCm + (size_t)r * BCSTR + h * NSTATE + c);
    }
    if (tid < SEGT)            sdt[tid] = dtv[((t0 + tid) * B_SZ + b) * NHEAD + h];
    else if (tid < 2 * SEGT)   sdec[tid - SEGT] = decayv[((t0 + tid - SEGT) * B_SZ + b) * NHEAD + h];
    __syncthreads();

    if (tid < 32) {
        float p = 1.f;
        for (int i = 3; i >= 0; --i) {
            int t = tid * 4 + i;
            sw[t] = sdt[t] * p;
            p *= sdec[t];
        }
        sP[tid] = p;
    }
    __syncthreads();
    if (tid == 0) {
        float suf = 1.f;
        for (int q = 31; q >= 0; --q) { float tmp = sP[q]; sP[q] = suf; suf *= tmp; }
    }
    __syncthreads();
    if (tid < 32) {
        float m = sP[tid];
        for (int i = 0; i < 4; ++i) sw[tid * 4 + i] *= m;
    }
    __syncthreads();

    float acc[4][8];
#pragma unroll
    for (int i = 0; i < 4; i++)
#pragma unroll
        for (int j = 0; j < 8; j++) acc[i][j] = 0.f;

    for (int t = 0; t < SEGT; ++t) {
        float w = sw[t];
        const u16* xp = &sx[t][pgrp * 4];
        const u16* bp = &sbm[t][oct * 8];
        float xv[4], bv[8];
#pragma unroll
        for (int i = 0; i < 4; i++) xv[i] = w * bf2f(xp[i]);
#pragma unroll
        for (int j = 0; j < 8; j++) bv[j] = bf2f(bp[j]);
#pragma unroll
        for (int i = 0; i < 4; i++)
#pragma unroll
            for (int j = 0; j < 8; j++)
                acc[i][j] = fmaf(xv[i], bv[j], acc[i][j]);
    }

    float* base = Hbuf + (size_t)seg * SLOT +
                  (((size_t)b * NHEAD + h) * PDIM + pgrp * 4) * NSTATE + oct * 8;
#pragma unroll
    for (int i = 0; i < 4; i++) {
        *(float4*)(base + (size_t)i * NSTATE)     = make_float4(acc[i][0], acc[i][1], acc[i][2], acc[i][3]);
        *(float4*)(base + (size_t)i * NSTATE + 4) = make_float4(acc[i][4], acc[i][5], acc[i][6], acc[i][7]);
    }
}

// ---------------- prefix combine -> bf16 prefix states Hbf ----------------
__global__ __launch_bounds__(256) void seg_prefix(const float* __restrict__ Hbuf,
                                                  const float* __restrict__ decayv,
                                                  u16* __restrict__ Hbf) {
    const int blk = blockIdx.x;
    const int b  = blk >> 6;
    const int h  = (blk >> 2) & 15;
    const int ec = blk & 3;
    const int tid = threadIdx.x;

    __shared__ float sA[NSEG];

    if (tid < 64 * (NSEG - 2)) {
        int s = 1 + (tid >> 6);
        int i = tid & 63;
        int t = s * SEGT + i * 2;
        float p = decayv[(t * B_SZ + b) * NHEAD + h] *
                  decayv[((t + 1) * B_SZ + b) * NHEAD + h];
        p *= __shfl_xor(p, 1);
        p *= __shfl_xor(p, 2);
        p *= __shfl_xor(p, 4);
        p *= __shfl_xor(p, 8);
        p *= __shfl_xor(p, 16);
        p *= __shfl_xor(p, 32);
        if (i == 0) sA[s] = p;
    }
    __syncthreads();

    const size_t base = (((size_t)b * NHEAD + h) * PDIM * NSTATE) + (size_t)ec * 2048 + tid * 8;
    float4 P0 = *(const float4*)(Hbuf + base);
    float4 P1 = *(const float4*)(Hbuf + base + 4);
    u16 pk[8];
    pk[0] = f2bf(P0.x); pk[1] = f2bf(P0.y); pk[2] = f2bf(P0.z); pk[3] = f2bf(P0.w);
    pk[4] = f2bf(P1.x); pk[5] = f2bf(P1.y); pk[6] = f2bf(P1.z); pk[7] = f2bf(P1.w);
    *(uint4*)(Hbf + base) = *(const uint4*)pk;
#pragma unroll
    for (int s = 1; s <= NSEG - 2; ++s) {
        float a = sA[s];
        const float* slot = Hbuf + (size_t)s * SLOT + base;
        float4 h0 = *(const float4*)(slot);
        float4 h1 = *(const float4*)(slot + 4);
        P0.x = fmaf(a, P0.x, h0.x); P0.y = fmaf(a, P0.y, h0.y);
        P0.z = fmaf(a, P0.z, h0.z); P0.w = fmaf(a, P0.w, h0.w);
        P1.x = fmaf(a, P1.x, h1.x); P1.y = fmaf(a, P1.y, h1.y);
        P1.z = fmaf(a, P1.z, h1.z); P1.w = fmaf(a, P1.w, h1.w);
        pk[0] = f2bf(P0.x); pk[1] = f2bf(P0.y); pk[2] = f2bf(P0.z); pk[3] = f2bf(P0.w);
        pk[4] = f2bf(P1.x); pk[5] = f2bf(P1.y); pk[6] = f2bf(P1.z); pk[7] = f2bf(P1.w);
        *(uint4*)(Hbf + (size_t)s * SLOT + base) = *(const uint4*)pk;
    }
}

// ---------------- chunk_scan: fused S' build + Y = exp(L).C@Hp^T + S'@X^T ----------------
__global__ __launch_bounds__(256) void chunk_scan(const u16* __restrict__ BCm,
                                                  const float* __restrict__ dtv,
                                                  const float* __restrict__ decayv,
                                                  const u16* __restrict__ Hbf,
                                                  u16* __restrict__ xb) {
    __shared__ __align__(16) u16 sB_[128][68];   // B [t'][n]
    __shared__ __align__(16) u16 sC_[128][68];   // C [t][n]
    __shared__ __align__(16) u16 sS[128][132];   // S' [t][t']
    __shared__ __align__(16) u16 sXT[128][36];   // X^T [p][k-tile]
    __shared__ float sdt[SEGT], sL[SEGT], sEL[SEGT], stmp[32];

    const int blk = blockIdx.x;
    const int seg = blk >> 7, b = (blk >> 4) & 7, h = blk & 15;
    const int tid = threadIdx.x;
    const int wave = tid >> 6, lane = tid & 63;
    const int quad = lane >> 4, lr = lane & 15;
    const int wm = wave & 1, wn = wave >> 1;
    const int t0 = seg * SEGT;

#pragma unroll
    for (int it = 0; it < 4; ++it) {
        int idx = tid + it * 256;
        int t = idx >> 3, c = (idx & 7) * 8;
        int r = (t0 + t) * B_SZ + b;
        *(uint4*)&sB_[t][c] = *(const uint4*)(BCm + (size_t)r * BCSTR + h * NSTATE + c);
        *(uint4*)&sC_[t][c] = *(const uint4*)(BCm + (size_t)r * BCSTR + 1024 + h * NSTATE + c);
    }
    if (tid < SEGT) sdt[tid] = dtv[((t0 + tid) * B_SZ + b) * NHEAD + h];
    else if (tid < 2 * SEGT) {
        int t = tid - SEGT;
        sL[t] = __logf(fmaxf(decayv[((t0 + t) * B_SZ + b) * NHEAD + h], 1e-30f));
    }
    __syncthreads();
    if (tid < 32) {
        float s = 0.f, v[4];
#pragma unroll
        for (int i = 0; i < 4; ++i) { s += sL[tid * 4 + i]; v[i] = s; }
        stmp[tid] = s;
#pragma unroll
        for (int i = 0; i < 4; ++i) sL[tid * 4 + i] = v[i];
    }
    __syncthreads();
    if (tid == 0) {
        float run = 0.f;
        for (int q = 0; q < 32; ++q) { float c2 = stmp[q]; stmp[q] = run; run += c2; }
    }
    __syncthreads();
    if (tid < 32) {
        float off = stmp[tid];
#pragma unroll
        for (int i = 0; i < 4; ++i) sL[tid * 4 + i] += off;
    }
    __syncthreads();
    if (tid < SEGT) sEL[tid] = __expf(sL[tid]);

    floatx4 accS[4][4];
#pragma unroll
    for (int i = 0; i < 4; i++)
#pragma unroll
        for (int j = 0; j < 4; j++)
#pragma unroll
            for (int r = 0; r < 4; r++) accS[i][j][r] = 0.f;
#pragma unroll
    for (int k0 = 0; k0 < 64; k0 += 32) {
        bf16x8 af[4], bfr[4];
#pragma unroll
        for (int i = 0; i < 4; i++)
            af[i] = *(const bf16x8*)&sB_[wm * 64 + i * 16 + lr][k0 + quad * 8];
#pragma unroll
        for (int j = 0; j < 4; j++)
            bfr[j] = *(const bf16x8*)&sC_[wn * 64 + j * 16 + lr][k0 + quad * 8];
#pragma unroll
        for (int i = 0; i < 4; i++)
#pragma unroll
            for (int j = 0; j < 4; j++)
                accS[i][j] = __builtin_amdgcn_mfma_f32_16x16x32_bf16(af[i], bfr[j], accS[i][j], 0, 0, 0);
    }
#pragma unroll
    for (int j = 0; j < 4; j++) {
        int tt = wn * 64 + j * 16 + lr;
        float Lt = sL[tt];
#pragma unroll
        for (int i = 0; i < 4; i++) {
#pragma unroll
            for (int r = 0; r < 4; r++) {
                int tp = wm * 64 + i * 16 + quad * 4 + r;
                float v = 0.f;
                if (tp <= tt) v = accS[i][j][r] * sdt[tp] * __expf(Lt - sL[tp]);
                sS[tt][tp] = f2bf(v);
            }
        }
    }

    floatx4 acc[4][4];
#pragma unroll
    for (int i = 0; i < 4; i++)
#pragma unroll
        for (int j = 0; j < 4; j++)
#pragma unroll
            for (int r = 0; r < 4; r++) acc[i][j][r] = 0.f;
    __syncthreads();
    if (seg > 0) {
        const u16* hbase = Hbf + (size_t)(seg - 1) * SLOT + (((size_t)b * NHEAD + h) * PDIM) * NSTATE;
#pragma unroll
        for (int k0 = 0; k0 < 64; k0 += 32) {
            bf16x8 af[4], bfr[4];
#pragma unroll
            for (int i = 0; i < 4; i++)
                af[i] = *(const bf16x8*)&sC_[wm * 64 + i * 16 + lr][k0 + quad * 8];
#pragma unroll
            for (int j = 0; j < 4; j++)
                bfr[j] = *(const bf16x8*)(hbase + (size_t)(wn * 64 + j * 16 + lr) * NSTATE + k0 + quad * 8);
#pragma unroll
            for (int i = 0; i < 4; i++)
#pragma unroll
                for (int j = 0; j < 4; j++)
                    acc[i][j] = __builtin_amdgcn_mfma_f32_16x16x32_bf16(af[i], bfr[j], acc[i][j], 0, 0, 0);
        }
#pragma unroll
        for (int i = 0; i < 4; i++) {
#pragma unroll
            for (int r = 0; r < 4; r++) {
                float el = sEL[wm * 64 + i * 16 + quad * 4 + r];
#pragma unroll
                for (int j = 0; j < 4; j++) acc[i][j][r] *= el;
            }
        }
    }

    const int px = tid & 127, koh = (tid >> 7) * 16;
    for (int kc = 0; kc < 128; kc += 32) {
        u16 xv[16];
#pragma unroll
        for (int j2 = 0; j2 < 16; ++j2) {
            int tp = kc + koh + j2;
            xv[j2] = xb[(size_t)((t0 + tp) * B_SZ + b) * D_IN + h * PDIM + px];
        }
        __syncthreads();
        *(uint4*)&sXT[px][koh]     = *(const uint4*)&xv[0];
        *(uint4*)&sXT[px][koh + 8] = *(const uint4*)&xv[8];
        __syncthreads();
        bf16x8 af[4], bfr[4];
#pragma unroll
        for (int i = 0; i < 4; i++)
            af[i] = *(const bf16x8*)&sS[wm * 64 + i * 16 + lr][kc + quad * 8];
#pragma unroll
        for (int j = 0; j < 4; j++)
            bfr[j] = *(const bf16x8*)&sXT[wn * 64 + j * 16 + lr][quad * 8];
#pragma unroll
        for (int i = 0; i < 4; i++)
#pragma unroll
            for (int j = 0; j < 4; j++)
                acc[i][j] = __builtin_amdgcn_mfma_f32_16x16x32_bf16(af[i], bfr[j], acc[i][j], 0, 0, 0);
    }

#pragma unroll
    for (int j = 0; j < 4; j++) {
        int p = wn * 64 + j * 16 + lr;
#pragma unroll
        for (int i = 0; i < 4; i++) {
#pragma unroll
            for (int r = 0; r < 4; r++) {
                int t = wm * 64 + i * 16 + quad * 4 + r;
                xb[(size_t)((t0 + t) * B_SZ + b) * D_IN + h * PDIM + p] = f2bf(acc[i][j][r]);
            }
        }
    }
}

// ---------------- launch ----------------
extern "C" void kernel_launch(void* const* d_in, const int* in_sizes, int n_in,
                              void* d_out, int out_size, void* d_ws, size_t ws_size,
                              hipStream_t stream) {
    const float* obs     = (const float*)d_in[0];
    const float* W_in    = (const float*)d_in[1];
    const float* b_in    = (const float*)d_in[2];
    const float* A_log   = (const float*)d_in[3];
    const float* dt_bias = (const float*)d_in[4];
    const float* W_dt    = (const float*)d_in[5];
    const float* W_B     = (const float*)d_in[6];
    const float* W_C     = (const float*)d_in[7];
    const float* W_yo    = (const float*)d_in[8];
    const float* b_yo    = (const float*)d_in[9];
    const float* W_head  = (const float*)d_in[10];
    const float* b_head  = (const float*)d_in[11];

    char* ws = (char*)d_ws;
    size_t o = 0;
    u16*   xb     = (u16*)(ws + o);   o += (size_t)ROWS * D_IN * 2;            // 16 MB (x, then y in-place)
    u16*   BCm    = (u16*)(ws + o);   o += (size_t)ROWS * BCSTR * 2;           // 17.8 MB (B | C | pad)
    float* dtv    = (float*)(ws + o); o += (size_t)ROWS * NHEAD * 4;
    float* decayv = (float*)(ws + o); o += (size_t)ROWS * NHEAD * 4;
    u16*   zb     = (u16*)(ws + o);   o += (size_t)ROWS * NUNITS * 2;          // 2 MB
    float* Hseg   = (float*)(ws + o); o += (size_t)(NSEG - 1) * SLOT * 4;      // 12 MB
    u16*   Hbf    = (u16*)(ws + o);   o += (size_t)(NSEG - 1) * SLOT * 2;      // 6 MB
    u16*   obsb   = (u16*)(ws + o);   o += (size_t)ROWS * OBS_D * 2;           // 2 MB
    u16*   WinT   = (u16*)(ws + o);   o += (size_t)D_IN * OBS_D * 2;           // 1 MB
    u16*   WBCT   = (u16*)(ws + o);   o += (size_t)BCN * D_IN * 2;             // 8 MB
    u16*   WdtT   = (u16*)(ws + o);   o += (size_t)NHEAD * D_IN * 2;           // 64 KB
    u16*   WyoT   = (u16*)(ws + o);   o += (size_t)NUNITS * D_IN * 2;          // 1 MB
    u16*   WheadT = (u16*)(ws + o);   o += (size_t)NACT * NUNITS * 2;

    // zero-work launch of the harness-required symbol (kept referenced)
    ActorAgent_27625229647898_kernel<<<dim3(1), 256, 0, stream>>>((float*)d_out, 0, 0.f);

    // ---- all weight prep in one launch ----
    prep<<<dim3(160 + 5136), 256, 0, stream>>>(obs, W_dt, W_in, W_B, W_C, W_yo, W_head,
                                               obsb, WinT, WBCT, WdtT, WyoT, WheadT);

    // ---- x = relu(obs @ W_in + b_in) -> bf16 ----
    gemm_bt128<1, 1, 1><<<dim3(32, 16), 256, 0, stream>>>(obsb, WinT, b_in, xb, ROWS, D_IN, OBS_D, D_IN);
    // ---- dt = softplus(x @ W_dt + dt_bias); decay = exp(-exp(A_log)*dt) ----
    dtdecay<<<dim3(256), 512, 0, stream>>>(xb, WdtT, dt_bias, A_log, dtv, decayv);
    // ---- B|C projection: N=2048 (512 blocks = 2/CU), ldc=2176 (non-pow2 stride) ----
    gemm_bt128<0, 1, 0><<<dim3(32, 16), 256, 0, stream>>>(xb, WBCT, (const float*)nullptr, BCm, ROWS, BCN, D_IN, BCSTR);
    // ---- scan: A) segment-local final states ----
    seg_state<<<dim3((NSEG - 1) * 128), 256, 0, stream>>>(xb, BCm, dtv, decayv, Hseg);
    //          B) prefix combine -> bf16 ----
    seg_prefix<<<dim3(512), 256, 0, stream>>>(Hseg, decayv, Hbf);
    //          C) fused S' + Y, in-place over xb ----
    chunk_scan<<<dim3(NSEG * 128), 256, 0, stream>>>(BCm, dtv, decayv, Hbf, xb);
    // ---- z = relu(y @ W_yo + b_yo) -> bf16 ----
    gemm_bt64<1, 1><<<dim3(64, 4), 256, 0, stream>>>(xb, WyoT, b_yo, zb, ROWS, NUNITS, D_IN);
    // ---- logits = z @ W_head + b_head -> d_out (fp32) ----
    gemm_bt64<0, 0><<<dim3(64, 1), 256, 0, stream>>>(zb, WheadT, b_head, (float*)d_out, ROWS, NACT, NUNITS);
}

// Round 13
// 218.806 us; speedup vs baseline: 1.0950x; 1.0634x over previous
//
#include <hip/hip_runtime.h>
#include <cstdint>
#include <cstddef>

typedef unsigned short u16;
typedef __attribute__((ext_vector_type(8))) __bf16 bf16x8;   // MFMA A/B operand
typedef __attribute__((ext_vector_type(4))) float floatx4;   // MFMA C/D operand

// dims
#define T_DIM   512
#define B_SZ    8
#define ROWS    4096      // T*B
#define OBS_D   256
#define D_IN    2048
#define NHEAD   16
#define NSTATE  64
#define PDIM    128
#define NUNITS  256
#define NACT    64
#define NSEG    4
#define SEGT    128       // T_DIM / NSEG
#define SLOT    (B_SZ * NHEAD * PDIM * NSTATE)   // 1048576 elems per seg-state slot
#define BCSTR   2176      // row stride of BCm (u16 elems; non-pow2 — r18 lesson)
#define BCN     2048      // computed columns (B|C)

__host__ __device__ __forceinline__ float bf2f(u16 u) {
    union { uint32_t i; float f; } v; v.i = ((uint32_t)u) << 16; return v.f;
}
__host__ __device__ __forceinline__ u16 f2bf(float f) {
    union { float f; uint32_t i; } v; v.f = f;
    uint32_t r = v.i + 0x7FFFu + ((v.i >> 16) & 1u);
    return (u16)(r >> 16);
}

// async 16B/lane global->LDS (m97 pattern). lds ptr must be wave-uniform.
__device__ __forceinline__ void glds16(const u16* g, u16* l) {
    __builtin_amdgcn_global_load_lds(
        (__attribute__((address_space(1))) void*)g,
        (__attribute__((address_space(3))) void*)l, 16, 0, 0);
}

// barrier that does NOT drain vmcnt (only LDS ordering) — lets global loads
// issued into registers stay in flight across serial LDS phases.
#define LBAR() do { asm volatile("s_waitcnt lgkmcnt(0)" ::: "memory"); \
                    __builtin_amdgcn_s_barrier(); } while (0)

// ---------------- harness-required symbol (zero-work launch keeps it referenced) ----------------
__global__ __launch_bounds__(256) void ActorAgent_27625229647898_kernel(
        float* __restrict__ out, int n, float v) {
    for (int i = blockIdx.x * 256 + threadIdx.x; i < n; i += gridDim.x * 256)
        out[i] = v;
}

// ---------------- prep: all weight converts + transposes in ONE launch ----------------
__global__ __launch_bounds__(256) void prep(const float* __restrict__ obs,
                                            const float* __restrict__ W_dt,
                                            const float* __restrict__ W_in,
                                            const float* __restrict__ W_B,
                                            const float* __restrict__ W_C,
                                            const float* __restrict__ W_yo,
                                            const float* __restrict__ W_head,
                                            u16* __restrict__ obsb,
                                            u16* __restrict__ WinT, u16* __restrict__ WBCT,
                                            u16* __restrict__ WdtT,
                                            u16* __restrict__ WyoT, u16* __restrict__ WheadT) {
    int bid = blockIdx.x;
    if (bid < 160) {
        const int NOBS = ROWS * OBS_D;             // 1048576
        const int NDT  = D_IN * NHEAD;             // 32768
        for (int i = bid * 256 + threadIdx.x; i < NOBS + NDT; i += 160 * 256) {
            if (i < NOBS) obsb[i] = f2bf(obs[i]);
            else {
                int j = i - NOBS;                  // j = k*16 + n
                int k = j >> 4, n = j & 15;
                WdtT[n * D_IN + k] = f2bf(W_dt[j]);
            }
        }
        return;
    }
    bid -= 160;
    const float* src; u16* dst; int R, C, bx, by;
    if (bid < 512)       { src = W_in;   dst = WinT;   R = 256;  C = 2048; bx = bid & 63; by = bid >> 6; }
    else if (bid < 2560) { int i = bid - 512;  src = W_B;  dst = WBCT; R = 2048; C = 1024; bx = i & 31; by = i >> 5; }
    else if (bid < 4608) { int i = bid - 2560; src = W_C;  dst = WBCT + (size_t)1024 * 2048; R = 2048; C = 1024; bx = i & 31; by = i >> 5; }
    else if (bid < 5120) { int i = bid - 4608; src = W_yo; dst = WyoT; R = 2048; C = 256;  bx = i & 7;  by = i >> 3; }
    else                 { int i = bid - 5120; src = W_head; dst = WheadT; R = 256; C = 64; bx = i & 1; by = i >> 1; }
    __shared__ float t[32][33];
    int c0 = bx * 32, r0 = by * 32;
    int tx = threadIdx.x & 31, ty = threadIdx.x >> 5;
#pragma unroll
    for (int i = 0; i < 32; i += 8)
        t[ty + i][tx] = src[(size_t)(r0 + ty + i) * C + c0 + tx];
    __syncthreads();
#pragma unroll
    for (int i = 0; i < 32; i += 8)
        dst[(size_t)(c0 + ty + i) * R + r0 + tx] = f2bf(t[tx][ty + i]);
}

// ---------------- bt128: 128x128 bf16 MFMA GEMM, B^T (N,K), BK=64 swizzled staging ----------------
// r29 (proven +5.6 us): BK=64, 2 buffers, ONE barrier + ONE vmcnt(0) per
// 64-K iter, 32 MFMA/barrier. Swizzle slot = chunk ^ (row&7) with
// pre-swizzled global source (rule #21); fragment read 4-way (hidden).
// History: r25 no in-kernel T2 at BK=32; r27 original grid (A L2-local);
// r28 no setprio (2-4 us cost at 2 waves/SIMD).
template <int ACT, int OUT_BF16, int HAS_BIAS>
__global__ __launch_bounds__(256) void gemm_bt128(const u16* __restrict__ A,
                                                  const u16* __restrict__ BT,
                                                  const float* __restrict__ bias,
                                                  void* __restrict__ Cout,
                                                  int M, int N, int K, int ldc) {
    __shared__ __align__(16) u16 sA[2][128 * 64];   // 2 x 16 KB
    __shared__ __align__(16) u16 sB[2][128 * 64];
    const int tid  = threadIdx.x;
    const int wave = tid >> 6, lane = tid & 63;
    const int quad = lane >> 4, lr = lane & 15;
    const int wm = wave & 1, wn = wave >> 1;
    const int m0 = blockIdx.x * 128, n0 = blockIdx.y * 128;
    const int r0 = wave * 32 + (lane >> 3);                   // staged row per lane
    const int kel = (((lane & 7) ^ ((lane >> 3) & 7))) * 8;   // swizzled k-chunk (u16)
    const int rsw = lr & 7;                                   // read-side slot XOR

    floatx4 acc[4][4];
#pragma unroll
    for (int i = 0; i < 4; i++)
#pragma unroll
        for (int j = 0; j < 4; j++)
#pragma unroll
            for (int r = 0; r < 4; r++) acc[i][j][r] = 0.f;

    const u16* apg = A + (size_t)(m0 + r0) * K + kel;
    const u16* bpg = BT + (size_t)(n0 + r0) * K + kel;
    const int ntk = K >> 6;   // K tiles (4 or 32 for our shapes; always >= 2)

#define STAGE128(t, sb) do {                                                   \
        int kk_ = (t) << 6;                                                    \
        _Pragma("unroll")                                                      \
        for (int g = 0; g < 4; ++g) {                                          \
            glds16(apg + (size_t)(g * 8) * K + kk_,                            \
                   &sA[sb][(wave * 32 + g * 8) * 64]);                         \
            glds16(bpg + (size_t)(g * 8) * K + kk_,                            \
                   &sB[sb][(wave * 32 + g * 8) * 64]);                         \
        }                                                                      \
    } while (0)

    STAGE128(0, 0);
    for (int t = 0; t < ntk; ++t) {
        const int s = t & 1;
        asm volatile("s_waitcnt vmcnt(0)" ::: "memory");   // tile t landed
        __builtin_amdgcn_s_barrier();   // all waves' tile-t loads visible;
                                        // all waves done reading tile t-1
        asm volatile("" ::: "memory");
        if (t + 1 < ntk) STAGE128(t + 1, s ^ 1);
#pragma unroll
        for (int ks = 0; ks < 2; ++ks) {
            bf16x8 af[4], bfr[4];
#pragma unroll
            for (int i = 0; i < 4; i++)
                af[i] = *(const bf16x8*)&sA[s][(wm * 64 + i * 16 + lr) * 64 + ((ks * 4 + quad) ^ rsw) * 8];
#pragma unroll
            for (int j = 0; j < 4; j++)
                bfr[j] = *(const bf16x8*)&sB[s][(wn * 64 + j * 16 + lr) * 64 + ((ks * 4 + quad) ^ rsw) * 8];
#pragma unroll
            for (int i = 0; i < 4; i++)
#pragma unroll
                for (int j = 0; j < 4; j++)
                    acc[i][j] = __builtin_amdgcn_mfma_f32_16x16x32_bf16(af[i], bfr[j], acc[i][j], 0, 0, 0);
        }
        asm volatile("" ::: "memory");
    }
#undef STAGE128
    // C/D layout: col = lane&15, row = quad*4 + reg
#pragma unroll
    for (int j = 0; j < 4; j++) {
        int col = n0 + wn * 64 + j * 16 + lr;
        float bvv = HAS_BIAS ? bias[col] : 0.f;
#pragma unroll
        for (int i = 0; i < 4; i++) {
#pragma unroll
            for (int r = 0; r < 4; r++) {
                int row = m0 + wm * 64 + i * 16 + quad * 4 + r;
                float v = acc[i][j][r] + bvv;
                if (ACT) v = fmaxf(v, 0.f);
                if (OUT_BF16) ((u16*)Cout)[(size_t)row * ldc + col] = f2bf(v);
                else          ((float*)Cout)[(size_t)row * ldc + col] = v;
            }
        }
    }
}

// ---------------- bt64: 64x64 bf16 MFMA GEMM, B^T layout, BK=128, 2-buffer 1-barrier ----------------
// r30: BK 64 -> 128 (r29 transform transferred). z-GEMM 32 -> 16 iters, head
// 4 -> 2; 16 MFMA per barrier. 16-slot swizzle: logical chunk c of row r
// lives at slot c ^ (r&15); source lane computes chunk = (lane&15) ^ (row&15)
// so the wave-uniform-dest glds writes linear LDS (rule #21). Read bank:
// 4*((slot^lr)%8) -> 2-way = free (m136). setprio kept (1 wave/SIMD here).
template <int ACT, int OUT_BF16>
__global__ __launch_bounds__(256) void gemm_bt64(const u16* __restrict__ A,
                                                 const u16* __restrict__ BT,
                                                 const float* __restrict__ bias,
                                                 void* __restrict__ Cout,
                                                 int M, int N, int K) {
    __shared__ __align__(16) u16 sA[2][64 * 128];  // 2 x 16 KB
    __shared__ __align__(16) u16 sB[2][64 * 128];
    const int tid  = threadIdx.x;
    const int wave = tid >> 6, lane = tid & 63;
    const int quad = lane >> 4, lr = lane & 15;
    const int m0 = blockIdx.x * 64, n0 = blockIdx.y * 64;
    const int rl = lane >> 4;        // row-within-quad-group for staging
    const int cl = lane & 15;        // chunk slot for staging

    floatx4 acc[4];
#pragma unroll
    for (int i = 0; i < 4; i++)
#pragma unroll
        for (int j = 0; j < 4; j++) acc[i][j] = 0.f;

    // per-lane staged (row, chunk) offsets for g = 0..3 (4 rows x 16 chunks per glds)
    size_t aoff[4], boff[4];
#pragma unroll
    for (int g = 0; g < 4; ++g) {
        int ro = g * 4 + rl;                 // row within wave's 16 rows (0..15)
        int ch = cl ^ ro;                    // swizzled chunk (involution)
        aoff[g] = (size_t)(m0 + wave * 16 + ro) * K + (size_t)ch * 8;
        boff[g] = (size_t)(n0 + wave * 16 + ro) * K + (size_t)ch * 8;
    }
    const int ntk = K >> 7;   // K tiles (16 for K=2048, 2 for K=256)

#define STAGE64(t, sb) do {                                                    \
        int kk_ = (t) << 7;                                                    \
        _Pragma("unroll")                                                      \
        for (int g = 0; g < 4; ++g) {                                          \
            glds16(A + aoff[g] + kk_,  &sA[sb][(wave * 16 + g * 4) * 128]);    \
            glds16(BT + boff[g] + kk_, &sB[sb][(wave * 16 + g * 4) * 128]);    \
        }                                                                      \
    } while (0)

    STAGE64(0, 0);
    for (int t = 0; t < ntk; ++t) {
        const int s = t & 1;
        asm volatile("s_waitcnt vmcnt(0)" ::: "memory");
        __builtin_amdgcn_s_barrier();
        asm volatile("" ::: "memory");
        if (t + 1 < ntk) STAGE64(t + 1, s ^ 1);
        __builtin_amdgcn_s_setprio(1);
#pragma unroll
        for (int ks = 0; ks < 4; ++ks) {
            bf16x8 af = *(const bf16x8*)&sA[s][(wave * 16 + lr) * 128 + ((ks * 4 + quad) ^ lr) * 8];
#pragma unroll
            for (int nt = 0; nt < 4; nt++) {
                bf16x8 bf = *(const bf16x8*)&sB[s][(nt * 16 + lr) * 128 + ((ks * 4 + quad) ^ lr) * 8];
                acc[nt] = __builtin_amdgcn_mfma_f32_16x16x32_bf16(af, bf, acc[nt], 0, 0, 0);
            }
        }
        __builtin_amdgcn_s_setprio(0);
        asm volatile("" ::: "memory");
    }
#undef STAGE64
#pragma unroll
    for (int nt = 0; nt < 4; nt++) {
        int col = n0 + nt * 16 + lr;
        float bvv = bias ? bias[col] : 0.f;
#pragma unroll
        for (int r = 0; r < 4; r++) {
            int row = m0 + wave * 16 + quad * 4 + r;
            float v = acc[nt][r] + bvv;
            if (ACT) v = fmaxf(v, 0.f);
            if (OUT_BF16) ((u16*)Cout)[(size_t)row * N + col] = f2bf(v);
            else          ((float*)Cout)[(size_t)row * N + col] = v;
        }
    }
}

// ---------------- dtdecay: dtraw = x @ W_dt, fused softplus + decay ----------------
__global__ __launch_bounds__(512) void dtdecay(const u16* __restrict__ xb,
                                               const u16* __restrict__ WdtT,
                                               const float* __restrict__ dt_bias,
                                               const float* __restrict__ A_log,
                                               float* __restrict__ dtv,
                                               float* __restrict__ decayv) {
    __shared__ __align__(16) u16 sw[NHEAD * D_IN];   // 64 KB, [h][k]
    const int tid = threadIdx.x;
#pragma unroll
    for (int i = 0; i < 8; ++i) {
        int idx = (tid + i * 512) * 8;
        *(uint4*)&sw[idx] = *(const uint4*)(WdtT + idx);
    }
    __syncthreads();
    const int wave = tid >> 6, lane = tid & 63;
    const int q = lane >> 4, lr = lane & 15;
    const int row0 = blockIdx.x * 16 + wave * 2;
    const u16* xp0 = xb + (size_t)row0 * D_IN;
    const u16* xp1 = xb + (size_t)(row0 + 1) * D_IN;
    float acc0[4] = {0.f, 0.f, 0.f, 0.f};
    float acc1[4] = {0.f, 0.f, 0.f, 0.f};
#pragma unroll 4
    for (int k0 = 0; k0 < 16; ++k0) {
        const int kk = k0 * 128 + lr * 8;
        uint4 xv0 = *(const uint4*)(xp0 + kk);
        uint4 xv1 = *(const uint4*)(xp1 + kk);
        const u16* xu0 = (const u16*)&xv0;
        const u16* xu1 = (const u16*)&xv1;
        float xf0[8], xf1[8];
#pragma unroll
        for (int j = 0; j < 8; ++j) { xf0[j] = bf2f(xu0[j]); xf1[j] = bf2f(xu1[j]); }
#pragma unroll
        for (int j = 0; j < 4; ++j) {
            uint4 wv = *(const uint4*)&sw[(q * 4 + j) * D_IN + kk];
            const u16* wu = (const u16*)&wv;
#pragma unroll
            for (int jj = 0; jj < 8; ++jj) {
                float wf = bf2f(wu[jj]);
                acc0[j] = fmaf(xf0[jj], wf, acc0[j]);
                acc1[j] = fmaf(xf1[jj], wf, acc1[j]);
            }
        }
    }
#pragma unroll
    for (int m = 1; m <= 8; m <<= 1)
#pragma unroll
        for (int j = 0; j < 4; ++j) {
            acc0[j] += __shfl_xor(acc0[j], m);
            acc1[j] += __shfl_xor(acc1[j], m);
        }
    if (lr == 0) {
#pragma unroll
        for (int j = 0; j < 4; ++j) {
            int h = q * 4 + j;
            float ae = expf(A_log[h]);
            float z0 = acc0[j] + dt_bias[h];
            float sp0 = (z0 > 20.f) ? z0 : log1pf(expf(z0));
            float z1 = acc1[j] + dt_bias[h];
            float sp1 = (z1 > 20.f) ? z1 : log1pf(expf(z1));
            dtv[row0 * NHEAD + h] = sp0;
            decayv[row0 * NHEAD + h] = expf(-ae * sp0);
            dtv[(row0 + 1) * NHEAD + h] = sp1;
            decayv[(row0 + 1) * NHEAD + h] = expf(-ae * sp1);
        }
    }
}

// ---------------- seg_state: segment-final states via MFMA ----------------
// r30 rewrite: H[p][n] = sum_t (w_t x_t[p]) B_t[n] is a 128x64x128 GEMM.
// Old version: VALU outer products (~4096 FMA + 1536 cvts/thread). New:
// stage SCALED+TRANSPOSED operands (sxw[p][t] = bf16(w_t*x_t[p]), sbT[n][t];
// pads 132/134 give MFMA-read bank spreads 2*lr / 3*lr = conflict-free) then
// 32 MFMA/wave. Global x/B loads are issued into registers BEFORE the serial
// prefix phases (T14) using lgkm-only barriers so they stay in flight.
// Precision: w*x rounds to bf16 pre-accumulation (downstream Hbf is bf16
// anyway) — ~0.4% relative on terms, random-sign across t.
__global__ __launch_bounds__(256) void seg_state(const u16* __restrict__ xw,
                                                 const u16* __restrict__ BCm,
                                                 const float* __restrict__ dtv,
                                                 const float* __restrict__ decayv,
                                                 float* __restrict__ Hbuf) {
    const int blk = blockIdx.x;
    const int seg = blk >> 7;
    const int b   = (blk >> 4) & 7;
    const int h   = blk & 15;
    const int tid = threadIdx.x;
    const int wave = tid >> 6, lane = tid & 63;
    const int quad = lane >> 4, lr = lane & 15;
    const int wm = wave & 1, wn = wave >> 1;

    __shared__ __align__(16) u16 sxw[PDIM][SEGT + 4];    // [p][t], stride 132
    __shared__ __align__(16) u16 sbT[NSTATE][SEGT + 6];  // [n][t], stride 134
    __shared__ float sw_[SEGT], sdt[SEGT], sdec[SEGT], sP[32];

    const int t0 = seg * SEGT;

    // ---- issue all global loads into registers first (stay in flight) ----
    uint4 xv4[8];
#pragma unroll
    for (int k = 0; k < 8; ++k) {
        int idx = tid + k * 256;
        int t = idx >> 4, c = (idx & 15) * 8;
        int r = (t0 + t) * B_SZ + b;
        xv4[k] = *(const uint4*)(xw + (size_t)r * D_IN + h * PDIM + c);
    }
    uint4 bv4[4];
#pragma unroll
    for (int k = 0; k < 4; ++k) {
        int idx = tid + k * 256;
        int t = idx >> 3, c = (idx & 7) * 8;
        int r = (t0 + t) * B_SZ + b;
        bv4[k] = *(const uint4*)(BCm + (size_t)r * BCSTR + h * NSTATE + c);
    }

    if (tid < SEGT)            sdt[tid] = dtv[((t0 + tid) * B_SZ + b) * NHEAD + h];
    else if (tid < 2 * SEGT)   sdec[tid - SEGT] = decayv[((t0 + tid - SEGT) * B_SZ + b) * NHEAD + h];
    LBAR();

    if (tid < 32) {
        float p = 1.f;
        for (int i = 3; i >= 0; --i) {
            int t = tid * 4 + i;
            sw_[t] = sdt[t] * p;
            p *= sdec[t];
        }
        sP[tid] = p;
    }
    LBAR();
    if (tid == 0) {
        float suf = 1.f;
        for (int q = 31; q >= 0; --q) { float tmp = sP[q]; sP[q] = suf; suf *= tmp; }
    }
    LBAR();
    if (tid < 32) {
        float m = sP[tid];
        for (int i = 0; i < 4; ++i) sw_[tid * 4 + i] *= m;
    }
    LBAR();

    // ---- scaled transpose writes: sxw[p][t] = bf16(w_t * x_t[p]); sbT[n][t] = B ----
#pragma unroll
    for (int k = 0; k < 8; ++k) {
        int idx = tid + k * 256;
        int t = idx >> 4, c = (idx & 15) * 8;
        float w = sw_[t];
        const u16* u = (const u16*)&xv4[k];
#pragma unroll
        for (int j = 0; j < 8; ++j)
            sxw[c + j][t] = f2bf(bf2f(u[j]) * w);
    }
#pragma unroll
    for (int k = 0; k < 4; ++k) {
        int idx = tid + k * 256;
        int t = idx >> 3, c = (idx & 7) * 8;
        const u16* u = (const u16*)&bv4[k];
#pragma unroll
        for (int j = 0; j < 8; ++j)
            sbT[c + j][t] = u[j];
    }
    LBAR();

    // ---- MFMA: M=128 (p, wm half x i), N=64 (n, wn half x j), K=128 (t) ----
    floatx4 acc[4][2];
#pragma unroll
    for (int i = 0; i < 4; i++)
#pragma unroll
        for (int j = 0; j < 2; j++)
#pragma unroll
            for (int r = 0; r < 4; r++) acc[i][j][r] = 0.f;
#pragma unroll
    for (int kk = 0; kk < 128; kk += 32) {
        bf16x8 af[4], bfr[2];
#pragma unroll
        for (int i = 0; i < 4; i++)
            af[i] = *(const bf16x8*)&sxw[wm * 64 + i * 16 + lr][kk + quad * 8];
#pragma unroll
        for (int j = 0; j < 2; j++)
            bfr[j] = *(const bf16x8*)&sbT[wn * 32 + j * 16 + lr][kk + quad * 8];
#pragma unroll
        for (int i = 0; i < 4; i++)
#pragma unroll
            for (int j = 0; j < 2; j++)
                acc[i][j] = __builtin_amdgcn_mfma_f32_16x16x32_bf16(af[i], bfr[j], acc[i][j], 0, 0, 0);
    }

    // C/D: col(n) = lane&15, row(p) = quad*4 + r
    float* base = Hbuf + (size_t)seg * SLOT + (((size_t)b * NHEAD + h) * PDIM) * NSTATE;
#pragma unroll
    for (int i = 0; i < 4; i++) {
#pragma unroll
        for (int j = 0; j < 2; j++) {
            int n = wn * 32 + j * 16 + lr;
#pragma unroll
            for (int r = 0; r < 4; r++) {
                int p = wm * 64 + i * 16 + quad * 4 + r;
                base[(size_t)p * NSTATE + n] = acc[i][j][r];
            }
        }
    }
}

// ---------------- prefix combine -> bf16 prefix states Hbf ----------------
__global__ __launch_bounds__(256) void seg_prefix(const float* __restrict__ Hbuf,
                                                  const float* __restrict__ decayv,
                                                  u16* __restrict__ Hbf) {
    const int blk = blockIdx.x;
    const int b  = blk >> 6;
    const int h  = (blk >> 2) & 15;
    const int ec = blk & 3;
    const int tid = threadIdx.x;

    __shared__ float sA[NSEG];

    if (tid < 64 * (NSEG - 2)) {
        int s = 1 + (tid >> 6);
        int i = tid & 63;
        int t = s * SEGT + i * 2;
        float p = decayv[(t * B_SZ + b) * NHEAD + h] *
                  decayv[((t + 1) * B_SZ + b) * NHEAD + h];
        p *= __shfl_xor(p, 1);
        p *= __shfl_xor(p, 2);
        p *= __shfl_xor(p, 4);
        p *= __shfl_xor(p, 8);
        p *= __shfl_xor(p, 16);
        p *= __shfl_xor(p, 32);
        if (i == 0) sA[s] = p;
    }
    __syncthreads();

    const size_t base = (((size_t)b * NHEAD + h) * PDIM * NSTATE) + (size_t)ec * 2048 + tid * 8;
    float4 P0 = *(const float4*)(Hbuf + base);
    float4 P1 = *(const float4*)(Hbuf + base + 4);
    u16 pk[8];
    pk[0] = f2bf(P0.x); pk[1] = f2bf(P0.y); pk[2] = f2bf(P0.z); pk[3] = f2bf(P0.w);
    pk[4] = f2bf(P1.x); pk[5] = f2bf(P1.y); pk[6] = f2bf(P1.z); pk[7] = f2bf(P1.w);
    *(uint4*)(Hbf + base) = *(const uint4*)pk;
#pragma unroll
    for (int s = 1; s <= NSEG - 2; ++s) {
        float a = sA[s];
        const float* slot = Hbuf + (size_t)s * SLOT + base;
        float4 h0 = *(const float4*)(slot);
        float4 h1 = *(const float4*)(slot + 4);
        P0.x = fmaf(a, P0.x, h0.x); P0.y = fmaf(a, P0.y, h0.y);
        P0.z = fmaf(a, P0.z, h0.z); P0.w = fmaf(a, P0.w, h0.w);
        P1.x = fmaf(a, P1.x, h1.x); P1.y = fmaf(a, P1.y, h1.y);
        P1.z = fmaf(a, P1.z, h1.z); P1.w = fmaf(a, P1.w, h1.w);
        pk[0] = f2bf(P0.x); pk[1] = f2bf(P0.y); pk[2] = f2bf(P0.z); pk[3] = f2bf(P0.w);
        pk[4] = f2bf(P1.x); pk[5] = f2bf(P1.y); pk[6] = f2bf(P1.z); pk[7] = f2bf(P1.w);
        *(uint4*)(Hbf + (size_t)s * SLOT + base) = *(const uint4*)pk;
    }
}

// ---------------- chunk_scan: fused S' build + Y = exp(L).C@Hp^T + S'@X^T ----------------
__global__ __launch_bounds__(256) void chunk_scan(const u16* __restrict__ BCm,
                                                  const float* __restrict__ dtv,
                                                  const float* __restrict__ decayv,
                                                  const u16* __restrict__ Hbf,
                                                  u16* __restrict__ xb) {
    __shared__ __align__(16) u16 sB_[128][68];   // B [t'][n]
    __shared__ __align__(16) u16 sC_[128][68];   // C [t][n]
    __shared__ __align__(16) u16 sS[128][132];   // S' [t][t']
    __shared__ __align__(16) u16 sXT[128][36];   // X^T [p][k-tile]
    __shared__ float sdt[SEGT], sL[SEGT], sEL[SEGT], stmp[32];

    const int blk = blockIdx.x;
    const int seg = blk >> 7, b = (blk >> 4) & 7, h = blk & 15;
    const int tid = threadIdx.x;
    const int wave = tid >> 6, lane = tid & 63;
    const int quad = lane >> 4, lr = lane & 15;
    const int wm = wave & 1, wn = wave >> 1;
    const int t0 = seg * SEGT;

#pragma unroll
    for (int it = 0; it < 4; ++it) {
        int idx = tid + it * 256;
        int t = idx >> 3, c = (idx & 7) * 8;
        int r = (t0 + t) * B_SZ + b;
        *(uint4*)&sB_[t][c] = *(const uint4*)(BCm + (size_t)r * BCSTR + h * NSTATE + c);
        *(uint4*)&sC_[t][c] = *(const uint4*)(BCm + (size_t)r * BCSTR + 1024 + h * NSTATE + c);
    }
    if (tid < SEGT) sdt[tid] = dtv[((t0 + tid) * B_SZ + b) * NHEAD + h];
    else if (tid < 2 * SEGT) {
        int t = tid - SEGT;
        sL[t] = __logf(fmaxf(decayv[((t0 + t) * B_SZ + b) * NHEAD + h], 1e-30f));
    }
    __syncthreads();
    if (tid < 32) {
        float s = 0.f, v[4];
#pragma unroll
        for (int i = 0; i < 4; ++i) { s += sL[tid * 4 + i]; v[i] = s; }
        stmp[tid] = s;
#pragma unroll
        for (int i = 0; i < 4; ++i) sL[tid * 4 + i] = v[i];
    }
    __syncthreads();
    if (tid == 0) {
        float run = 0.f;
        for (int q = 0; q < 32; ++q) { float c2 = stmp[q]; stmp[q] = run; run += c2; }
    }
    __syncthreads();
    if (tid < 32) {
        float off = stmp[tid];
#pragma unroll
        for (int i = 0; i < 4; ++i) sL[tid * 4 + i] += off;
    }
    __syncthreads();
    if (tid < SEGT) sEL[tid] = __expf(sL[tid]);

    floatx4 accS[4][4];
#pragma unroll
    for (int i = 0; i < 4; i++)
#pragma unroll
        for (int j = 0; j < 4; j++)
#pragma unroll
            for (int r = 0; r < 4; r++) accS[i][j][r] = 0.f;
#pragma unroll
    for (int k0 = 0; k0 < 64; k0 += 32) {
        bf16x8 af[4], bfr[4];
#pragma unroll
        for (int i = 0; i < 4; i++)
            af[i] = *(const bf16x8*)&sB_[wm * 64 + i * 16 + lr][k0 + quad * 8];
#pragma unroll
        for (int j = 0; j < 4; j++)
            bfr[j] = *(const bf16x8*)&sC_[wn * 64 + j * 16 + lr][k0 + quad * 8];
#pragma unroll
        for (int i = 0; i < 4; i++)
#pragma unroll
            for (int j = 0; j < 4; j++)
                accS[i][j] = __builtin_amdgcn_mfma_f32_16x16x32_bf16(af[i], bfr[j], accS[i][j], 0, 0, 0);
    }
#pragma unroll
    for (int j = 0; j < 4; j++) {
        int tt = wn * 64 + j * 16 + lr;
        float Lt = sL[tt];
#pragma unroll
        for (int i = 0; i < 4; i++) {
#pragma unroll
            for (int r = 0; r < 4; r++) {
                int tp = wm * 64 + i * 16 + quad * 4 + r;
                float v = 0.f;
                if (tp <= tt) v = accS[i][j][r] * sdt[tp] * __expf(Lt - sL[tp]);
                sS[tt][tp] = f2bf(v);
            }
        }
    }

    floatx4 acc[4][4];
#pragma unroll
    for (int i = 0; i < 4; i++)
#pragma unroll
        for (int j = 0; j < 4; j++)
#pragma unroll
            for (int r = 0; r < 4; r++) acc[i][j][r] = 0.f;
    __syncthreads();
    if (seg > 0) {
        const u16* hbase = Hbf + (size_t)(seg - 1) * SLOT + (((size_t)b * NHEAD + h) * PDIM) * NSTATE;
#pragma unroll
        for (int k0 = 0; k0 < 64; k0 += 32) {
            bf16x8 af[4], bfr[4];
#pragma unroll
            for (int i = 0; i < 4; i++)
                af[i] = *(const bf16x8*)&sC_[wm * 64 + i * 16 + lr][k0 + quad * 8];
#pragma unroll
            for (int j = 0; j < 4; j++)
                bfr[j] = *(const bf16x8*)(hbase + (size_t)(wn * 64 + j * 16 + lr) * NSTATE + k0 + quad * 8);
#pragma unroll
            for (int i = 0; i < 4; i++)
#pragma unroll
                for (int j = 0; j < 4; j++)
                    acc[i][j] = __builtin_amdgcn_mfma_f32_16x16x32_bf16(af[i], bfr[j], acc[i][j], 0, 0, 0);
        }
#pragma unroll
        for (int i = 0; i < 4; i++) {
#pragma unroll
            for (int r = 0; r < 4; r++) {
                float el = sEL[wm * 64 + i * 16 + quad * 4 + r];
#pragma unroll
                for (int j = 0; j < 4; j++) acc[i][j][r] *= el;
            }
        }
    }

    const int px = tid & 127, koh = (tid >> 7) * 16;
    for (int kc = 0; kc < 128; kc += 32) {
        u16 xv[16];
#pragma unroll
        for (int j2 = 0; j2 < 16; ++j2) {
            int tp = kc + koh + j2;
            xv[j2] = xb[(size_t)((t0 + tp) * B_SZ + b) * D_IN + h * PDIM + px];
        }
        __syncthreads();
        *(uint4*)&sXT[px][koh]     = *(const uint4*)&xv[0];
        *(uint4*)&sXT[px][koh + 8] = *(const uint4*)&xv[8];
        __syncthreads();
        bf16x8 af[4], bfr[4];
#pragma unroll
        for (int i = 0; i < 4; i++)
            af[i] = *(const bf16x8*)&sS[wm * 64 + i * 16 + lr][kc + quad * 8];
#pragma unroll
        for (int j = 0; j < 4; j++)
            bfr[j] = *(const bf16x8*)&sXT[wn * 64 + j * 16 + lr][quad * 8];
#pragma unroll
        for (int i = 0; i < 4; i++)
#pragma unroll
            for (int j = 0; j < 4; j++)
                acc[i][j] = __builtin_amdgcn_mfma_f32_16x16x32_bf16(af[i], bfr[j], acc[i][j], 0, 0, 0);
    }

#pragma unroll
    for (int j = 0; j < 4; j++) {
        int p = wn * 64 + j * 16 + lr;
#pragma unroll
        for (int i = 0; i < 4; i++) {
#pragma unroll
            for (int r = 0; r < 4; r++) {
                int t = wm * 64 + i * 16 + quad * 4 + r;
                xb[(size_t)((t0 + t) * B_SZ + b) * D_IN + h * PDIM + p] = f2bf(acc[i][j][r]);
            }
        }
    }
}

// ---------------- launch ----------------
extern "C" void kernel_launch(void* const* d_in, const int* in_sizes, int n_in,
                              void* d_out, int out_size, void* d_ws, size_t ws_size,
                              hipStream_t stream) {
    const float* obs     = (const float*)d_in[0];
    const float* W_in    = (const float*)d_in[1];
    const float* b_in    = (const float*)d_in[2];
    const float* A_log   = (const float*)d_in[3];
    const float* dt_bias = (const float*)d_in[4];
    const float* W_dt    = (const float*)d_in[5];
    const float* W_B     = (const float*)d_in[6];
    const float* W_C     = (const float*)d_in[7];
    const float* W_yo    = (const float*)d_in[8];
    const float* b_yo    = (const float*)d_in[9];
    const float* W_head  = (const float*)d_in[10];
    const float* b_head  = (const float*)d_in[11];

    char* ws = (char*)d_ws;
    size_t o = 0;
    u16*   xb     = (u16*)(ws + o);   o += (size_t)ROWS * D_IN * 2;            // 16 MB (x, then y in-place)
    u16*   BCm    = (u16*)(ws + o);   o += (size_t)ROWS * BCSTR * 2;           // 17.8 MB (B | C | pad)
    float* dtv    = (float*)(ws + o); o += (size_t)ROWS * NHEAD * 4;
    float* decayv = (float*)(ws + o); o += (size_t)ROWS * NHEAD * 4;
    u16*   zb     = (u16*)(ws + o);   o += (size_t)ROWS * NUNITS * 2;          // 2 MB
    float* Hseg   = (float*)(ws + o); o += (size_t)(NSEG - 1) * SLOT * 4;      // 12 MB
    u16*   Hbf    = (u16*)(ws + o);   o += (size_t)(NSEG - 1) * SLOT * 2;      // 6 MB
    u16*   obsb   = (u16*)(ws + o);   o += (size_t)ROWS * OBS_D * 2;           // 2 MB
    u16*   WinT   = (u16*)(ws + o);   o += (size_t)D_IN * OBS_D * 2;           // 1 MB
    u16*   WBCT   = (u16*)(ws + o);   o += (size_t)BCN * D_IN * 2;             // 8 MB
    u16*   WdtT   = (u16*)(ws + o);   o += (size_t)NHEAD * D_IN * 2;           // 64 KB
    u16*   WyoT   = (u16*)(ws + o);   o += (size_t)NUNITS * D_IN * 2;          // 1 MB
    u16*   WheadT = (u16*)(ws + o);   o += (size_t)NACT * NUNITS * 2;

    // zero-work launch of the harness-required symbol (kept referenced)
    ActorAgent_27625229647898_kernel<<<dim3(1), 256, 0, stream>>>((float*)d_out, 0, 0.f);

    // ---- all weight prep in one launch ----
    prep<<<dim3(160 + 5136), 256, 0, stream>>>(obs, W_dt, W_in, W_B, W_C, W_yo, W_head,
                                               obsb, WinT, WBCT, WdtT, WyoT, WheadT);

    // ---- x = relu(obs @ W_in + b_in) -> bf16 ----
    gemm_bt128<1, 1, 1><<<dim3(32, 16), 256, 0, stream>>>(obsb, WinT, b_in, xb, ROWS, D_IN, OBS_D, D_IN);
    // ---- dt = softplus(x @ W_dt + dt_bias); decay = exp(-exp(A_log)*dt) ----
    dtdecay<<<dim3(256), 512, 0, stream>>>(xb, WdtT, dt_bias, A_log, dtv, decayv);
    // ---- B|C projection: N=2048 (512 blocks = 2/CU), ldc=2176 (non-pow2 stride) ----
    gemm_bt128<0, 1, 0><<<dim3(32, 16), 256, 0, stream>>>(xb, WBCT, (const float*)nullptr, BCm, ROWS, BCN, D_IN, BCSTR);
    // ---- scan: A) segment-local final states (MFMA) ----
    seg_state<<<dim3((NSEG - 1) * 128), 256, 0, stream>>>(xb, BCm, dtv, decayv, Hseg);
    //          B) prefix combine -> bf16 ----
    seg_prefix<<<dim3(512), 256, 0, stream>>>(Hseg, decayv, Hbf);
    //          C) fused S' + Y, in-place over xb ----
    chunk_scan<<<dim3(NSEG * 128), 256, 0, stream>>>(BCm, dtv, decayv, Hbf, xb);
    // ---- z = relu(y @ W_yo + b_yo) -> bf16 ----
    gemm_bt64<1, 1><<<dim3(64, 4), 256, 0, stream>>>(xb, WyoT, b_yo, zb, ROWS, NUNITS, D_IN);
    // ---- logits = z @ W_head + b_head -> d_out (fp32) ----
    gemm_bt64<0, 0><<<dim3(64, 1), 256, 0, stream>>>(zb, WheadT, b_head, (float*)d_out, ROWS, NACT, NUNITS);
}